// Round 1
// baseline (1191.792 us; speedup 1.0000x reference)
//
#include <hip/hip_runtime.h>
#include <math.h>

#define N_NODES 50000
#define N_EDGES 1600000
#define HDIM 128
#define NGRAPH 512
#define NCLS 10

// ---------------- init ----------------
__global__ __launch_bounds__(256) void init_k(float* deg, int* cntN, int* fill, float* pool, int* cntG) {
  int i = blockIdx.x * 256 + threadIdx.x;
  if (i < N_NODES) { deg[i] = 1.0f; cntN[i] = 0; fill[i] = 0; }  // deg starts at 1.0 (self-loop weight)
  if (i < NGRAPH * HDIM) pool[i] = 0.f;
  if (i < NGRAPH) cntG[i] = 0;
}

// ---------------- degree + in-edge histogram ----------------
__global__ __launch_bounds__(256) void edge_deg_k(const int* __restrict__ ei, const float* __restrict__ ew,
                                                  float* deg, int* cntN) {
  int e = blockIdx.x * 256 + threadIdx.x;
  if (e < N_EDGES) {
    int c = ei[N_EDGES + e];             // col = target
    atomicAdd(&deg[c], ew[e]);
    atomicAdd(&cntN[c], 1);
  }
}

__global__ __launch_bounds__(256) void dinv_k(float* deg) {
  int i = blockIdx.x * 256 + threadIdx.x;
  if (i < N_NODES) deg[i] = rsqrtf(deg[i]);   // deg >= 1 always
}

// ---------------- exclusive scan of cntN -> off (2-level) ----------------
__global__ __launch_bounds__(256) void scan1_k(const int* __restrict__ cnt, int* off, int* bsum) {
  __shared__ int sdata[256];
  int t = threadIdx.x;
  int base = blockIdx.x * 1024 + t * 4;
  int v0 = (base + 0 < N_NODES) ? cnt[base + 0] : 0;
  int v1 = (base + 1 < N_NODES) ? cnt[base + 1] : 0;
  int v2 = (base + 2 < N_NODES) ? cnt[base + 2] : 0;
  int v3 = (base + 3 < N_NODES) ? cnt[base + 3] : 0;
  int s0 = v0, s1 = s0 + v1, s2 = s1 + v2, s3 = s2 + v3;
  sdata[t] = s3;
  __syncthreads();
  for (int d = 1; d < 256; d <<= 1) {
    int x = (t >= d) ? sdata[t - d] : 0;
    __syncthreads();
    sdata[t] += x;
    __syncthreads();
  }
  int excl = sdata[t] - s3;
  if (base + 0 < N_NODES) off[base + 0] = excl;
  if (base + 1 < N_NODES) off[base + 1] = excl + s0;
  if (base + 2 < N_NODES) off[base + 2] = excl + s1;
  if (base + 3 < N_NODES) off[base + 3] = excl + s2;
  if (t == 255) bsum[blockIdx.x] = sdata[255];
}

__global__ void scan2_k(int* bsum, int nb) {
  if (threadIdx.x == 0 && blockIdx.x == 0) {
    int acc = 0;
    for (int i = 0; i < nb; ++i) { int v = bsum[i]; bsum[i] = acc; acc += v; }
  }
}

__global__ __launch_bounds__(256) void scan3_k(int* off, const int* __restrict__ bsum) {
  int i = blockIdx.x * 256 + threadIdx.x;
  if (i < N_NODES) off[i] += bsum[i >> 10];
  if (i == 0) off[N_NODES] = N_EDGES;
}

// ---------------- CSR scatter ----------------
__global__ __launch_bounds__(256) void scatter_k(const int* __restrict__ ei, const float* __restrict__ ew,
                                                 const float* __restrict__ dinv, const int* __restrict__ off,
                                                 int* fill, int* crow, float* cnorm) {
  int e = blockIdx.x * 256 + threadIdx.x;
  if (e < N_EDGES) {
    int r = ei[e];
    int c = ei[N_EDGES + e];
    int pos = off[c] + atomicAdd(&fill[c], 1);
    crow[pos] = r;
    cnorm[pos] = dinv[r] * ew[e] * dinv[c];
  }
}

// ---------------- GEMM: out[n,o] = sum_i in[n,i] * W[o,i] ----------------
// 256 threads = 4 waves; each wave does 4 nodes/iter, 8 iters -> 128 nodes/block.
__global__ __launch_bounds__(256) void gemm_k(const float* __restrict__ in, const float* __restrict__ W,
                                              float* __restrict__ out) {
  __shared__ float Wt[128][129];        // Wt[i][o] = W[o*128+i], padded -> conflict-free
  __shared__ float hb[4][4][128];
  int t = threadIdx.x;
  for (int idx = t; idx < HDIM * HDIM; idx += 256) {
    int o = idx >> 7, i = idx & 127;
    Wt[i][o] = W[idx];
  }
  __syncthreads();
  int wave = t >> 6, lane = t & 63;
  for (int j = 0; j < 8; ++j) {
    int n0 = blockIdx.x * 128 + j * 16 + wave * 4;
    for (int q = 0; q < 8; ++q) {
      int idx = q * 64 + lane;          // 0..511
      int rn = idx >> 7, ii = idx & 127;
      int n = n0 + rn;
      hb[wave][rn][ii] = (n < N_NODES) ? in[n * HDIM + ii] : 0.f;
    }
    // same-wave LDS write->read: ordered by waitcnt, no barrier needed
    float a00 = 0.f, a01 = 0.f, a10 = 0.f, a11 = 0.f;
    float a20 = 0.f, a21 = 0.f, a30 = 0.f, a31 = 0.f;
    for (int i = 0; i < HDIM; ++i) {
      float w0 = Wt[i][lane], w1 = Wt[i][lane + 64];
      float h0 = hb[wave][0][i], h1 = hb[wave][1][i];
      float h2 = hb[wave][2][i], h3 = hb[wave][3][i];
      a00 += h0 * w0; a01 += h0 * w1;
      a10 += h1 * w0; a11 += h1 * w1;
      a20 += h2 * w0; a21 += h2 * w1;
      a30 += h3 * w0; a31 += h3 * w1;
    }
    if (n0 + 0 < N_NODES) { out[(n0 + 0) * HDIM + lane] = a00; out[(n0 + 0) * HDIM + 64 + lane] = a01; }
    if (n0 + 1 < N_NODES) { out[(n0 + 1) * HDIM + lane] = a10; out[(n0 + 1) * HDIM + 64 + lane] = a11; }
    if (n0 + 2 < N_NODES) { out[(n0 + 2) * HDIM + lane] = a20; out[(n0 + 2) * HDIM + 64 + lane] = a21; }
    if (n0 + 3 < N_NODES) { out[(n0 + 3) * HDIM + lane] = a30; out[(n0 + 3) * HDIM + 64 + lane] = a31; }
  }
}

// ---------------- aggregate: out[c] = elu( dinv[c]^2*hw[c] + sum_csr norm*hw[row] + b ) ----------------
__global__ __launch_bounds__(128) void aggregate_k(const float* __restrict__ hw, const float* __restrict__ dinv,
                                                   const int* __restrict__ off, const int* __restrict__ crow,
                                                   const float* __restrict__ cnorm, const float* __restrict__ bias,
                                                   float* __restrict__ out) {
  int c = blockIdx.x;
  int f = threadIdx.x;
  float di = dinv[c];
  float acc = di * di * hw[c * HDIM + f];
  int s = off[c], e = off[c + 1];
  for (int k = s; k < e; ++k) {
    int r = crow[k];
    float w = cnorm[k];
    acc += w * hw[r * HDIM + f];
  }
  acc += bias[f];
  out[c * HDIM + f] = (acc > 0.f) ? acc : expm1f(acc);
}

// ---------------- mean-pool (batch sorted: run-length accumulate, flush on change) ----------------
__global__ __launch_bounds__(128) void pool_k(const float* __restrict__ h, const int* __restrict__ batch,
                                              float* pool, int* cntG) {
  int f = threadIdx.x;
  const int nper = (N_NODES + gridDim.x - 1) / gridDim.x;
  int s = blockIdx.x * nper;
  int e = min(s + nper, N_NODES);
  if (s >= e) return;
  float acc = 0.f;
  int cur = batch[s], cnt = 0;
  for (int n = s; n < e; ++n) {
    int b = batch[n];
    if (b != cur) {
      atomicAdd(&pool[cur * HDIM + f], acc);
      if (f == 0) atomicAdd(&cntG[cur], cnt);
      acc = 0.f; cnt = 0; cur = b;
    }
    acc += h[n * HDIM + f];
    cnt++;
  }
  atomicAdd(&pool[cur * HDIM + f], acc);
  if (f == 0) atomicAdd(&cntG[cur], cnt);
}

// ---------------- head: mean, fc1+elu, fc2, log_softmax ----------------
__global__ __launch_bounds__(128) void head_k(const float* __restrict__ pool, const int* __restrict__ cntG,
                                              const float* __restrict__ fc1w, const float* __restrict__ fc1b,
                                              const float* __restrict__ fc2w, const float* __restrict__ fc2b,
                                              float* __restrict__ out) {
  __shared__ float p[HDIM];
  __shared__ float z1[HDIM];
  __shared__ float z2[NCLS];
  int g = blockIdx.x, t = threadIdx.x;
  float c = (float)max(cntG[g], 1);
  p[t] = pool[g * HDIM + t] / c;
  __syncthreads();
  float a = fc1b[t];
  for (int i = 0; i < HDIM; ++i) a += p[i] * fc1w[t * HDIM + i];
  z1[t] = (a > 0.f) ? a : expm1f(a);
  __syncthreads();
  if (t < NCLS) {
    float a2 = fc2b[t];
    for (int i = 0; i < HDIM; ++i) a2 += z1[i] * fc2w[t * HDIM + i];
    z2[t] = a2;
  }
  __syncthreads();
  if (t == 0) {
    float m = -1e30f;
    for (int i = 0; i < NCLS; ++i) m = fmaxf(m, z2[i]);
    float s2 = 0.f;
    for (int i = 0; i < NCLS; ++i) s2 += expf(z2[i] - m);
    float l = logf(s2);
    for (int i = 0; i < NCLS; ++i) out[g * NCLS + i] = z2[i] - m - l;
  }
}

// ---------------- launch ----------------
static inline size_t align256(size_t x) { return (x + 255) & ~(size_t)255; }

extern "C" void kernel_launch(void* const* d_in, const int* in_sizes, int n_in,
                              void* d_out, int out_size, void* d_ws, size_t ws_size,
                              hipStream_t stream) {
  const float* x     = (const float*)d_in[0];
  const int*   ei    = (const int*)d_in[1];
  const float* ew    = (const float*)d_in[2];
  const int*   batch = (const int*)d_in[3];
  const float* Wl[4] = { (const float*)d_in[4], (const float*)d_in[6], (const float*)d_in[8], (const float*)d_in[10] };
  const float* bl[4] = { (const float*)d_in[5], (const float*)d_in[7], (const float*)d_in[9], (const float*)d_in[11] };
  const float* fc1w = (const float*)d_in[12];
  const float* fc1b = (const float*)d_in[13];
  const float* fc2w = (const float*)d_in[14];
  const float* fc2b = (const float*)d_in[15];
  float* out = (float*)d_out;

  char* ws = (char*)d_ws;
  size_t o = 0;
  float* buf0  = (float*)(ws + o); o = align256(o + (size_t)N_NODES * HDIM * 4);
  float* buf1  = (float*)(ws + o); o = align256(o + (size_t)N_NODES * HDIM * 4);
  int*   crow  = (int*)  (ws + o); o = align256(o + (size_t)N_EDGES * 4);
  float* cnorm = (float*)(ws + o); o = align256(o + (size_t)N_EDGES * 4);
  float* deg   = (float*)(ws + o); o = align256(o + (size_t)N_NODES * 4);   // becomes dinv in place
  int*   cntN  = (int*)  (ws + o); o = align256(o + (size_t)N_NODES * 4);
  int*   off   = (int*)  (ws + o); o = align256(o + (size_t)(N_NODES + 1) * 4);
  int*   fill  = (int*)  (ws + o); o = align256(o + (size_t)N_NODES * 4);
  int*   bsum  = (int*)  (ws + o); o = align256(o + 4096);
  float* pool  = (float*)(ws + o); o = align256(o + (size_t)NGRAPH * HDIM * 4);
  int*   cntG  = (int*)  (ws + o); o = align256(o + (size_t)NGRAPH * 4);

  const int nscan = (N_NODES + 1023) / 1024;                 // 49

  init_k<<<(NGRAPH * HDIM + 255) / 256, 256, 0, stream>>>(deg, cntN, fill, pool, cntG);
  edge_deg_k<<<(N_EDGES + 255) / 256, 256, 0, stream>>>(ei, ew, deg, cntN);
  dinv_k<<<(N_NODES + 255) / 256, 256, 0, stream>>>(deg);
  scan1_k<<<nscan, 256, 0, stream>>>(cntN, off, bsum);
  scan2_k<<<1, 64, 0, stream>>>(bsum, nscan);
  scan3_k<<<(N_NODES + 255) / 256, 256, 0, stream>>>(off, bsum);
  scatter_k<<<(N_EDGES + 255) / 256, 256, 0, stream>>>(ei, ew, deg, off, fill, crow, cnorm);

  const float* hin = x;
  for (int l = 0; l < 4; ++l) {
    gemm_k<<<(N_NODES + 127) / 128, 256, 0, stream>>>(hin, Wl[l], buf1);
    aggregate_k<<<N_NODES, 128, 0, stream>>>(buf1, deg, off, crow, cnorm, bl[l], buf0);
    hin = buf0;
  }

  pool_k<<<256, 128, 0, stream>>>(buf0, batch, pool, cntG);
  head_k<<<NGRAPH, 128, 0, stream>>>(pool, cntG, fc1w, fc1b, fc2w, fc2b, out);
}

// Round 2
// 588.477 us; speedup vs baseline: 2.0252x; 2.0252x over previous
//
#include <hip/hip_runtime.h>
#include <math.h>

#define N_NODES 50000
#define N_EDGES 1600000
#define HDIM 128
#define NGRAPH 512
#define NCLS 10

typedef __attribute__((ext_vector_type(8))) short short8v;
typedef __attribute__((ext_vector_type(4))) float float4v;

// bf16 helpers (packed pair in a uint: lo = feature 2t, hi = feature 2t+1)
__device__ inline float blo(unsigned int v) { return __uint_as_float(v << 16); }
__device__ inline float bhi(unsigned int v) { return __uint_as_float(v & 0xffff0000u); }
__device__ inline unsigned short f2b(float f) {
  unsigned int u = __float_as_uint(f);
  unsigned int r = u + 0x7fffu + ((u >> 16) & 1u);   // RNE
  return (unsigned short)(r >> 16);
}

// ---------------- init ----------------
__global__ __launch_bounds__(256) void init_k(float* deg, int* cntN, int* fill, float* pool, int* cntG) {
  int i = blockIdx.x * 256 + threadIdx.x;
  if (i < N_NODES) { deg[i] = 1.0f; cntN[i] = 0; fill[i] = 0; }
  if (i < NGRAPH * HDIM) pool[i] = 0.f;
  if (i < NGRAPH) cntG[i] = 0;
}

// ---------------- fp32 -> bf16 cast (4 elems/thread) ----------------
__global__ __launch_bounds__(256) void cast4_k(const float* __restrict__ in, unsigned short* __restrict__ out, int n4) {
  int i = blockIdx.x * 256 + threadIdx.x;
  if (i < n4) {
    float4 v = ((const float4*)in)[i];
    ushort4 o;
    o.x = f2b(v.x); o.y = f2b(v.y); o.z = f2b(v.z); o.w = f2b(v.w);
    ((ushort4*)out)[i] = o;
  }
}

// ---------------- degree + in-edge histogram ----------------
__global__ __launch_bounds__(256) void edge_deg_k(const int* __restrict__ ei, const float* __restrict__ ew,
                                                  float* deg, int* cntN) {
  int e = blockIdx.x * 256 + threadIdx.x;
  if (e < N_EDGES) {
    int c = ei[N_EDGES + e];
    atomicAdd(&deg[c], ew[e]);
    atomicAdd(&cntN[c], 1);
  }
}

__global__ __launch_bounds__(256) void dinv_k(float* deg) {
  int i = blockIdx.x * 256 + threadIdx.x;
  if (i < N_NODES) deg[i] = rsqrtf(deg[i]);
}

// ---------------- exclusive scan ----------------
__global__ __launch_bounds__(256) void scan1_k(const int* __restrict__ cnt, int* off, int* bsum) {
  __shared__ int sdata[256];
  int t = threadIdx.x;
  int base = blockIdx.x * 1024 + t * 4;
  int v0 = (base + 0 < N_NODES) ? cnt[base + 0] : 0;
  int v1 = (base + 1 < N_NODES) ? cnt[base + 1] : 0;
  int v2 = (base + 2 < N_NODES) ? cnt[base + 2] : 0;
  int v3 = (base + 3 < N_NODES) ? cnt[base + 3] : 0;
  int s0 = v0, s1 = s0 + v1, s2 = s1 + v2, s3 = s2 + v3;
  sdata[t] = s3;
  __syncthreads();
  for (int d = 1; d < 256; d <<= 1) {
    int x = (t >= d) ? sdata[t - d] : 0;
    __syncthreads();
    sdata[t] += x;
    __syncthreads();
  }
  int excl = sdata[t] - s3;
  if (base + 0 < N_NODES) off[base + 0] = excl;
  if (base + 1 < N_NODES) off[base + 1] = excl + s0;
  if (base + 2 < N_NODES) off[base + 2] = excl + s1;
  if (base + 3 < N_NODES) off[base + 3] = excl + s2;
  if (t == 255) bsum[blockIdx.x] = sdata[255];
}

__global__ void scan2_k(int* bsum, int nb) {
  if (threadIdx.x == 0 && blockIdx.x == 0) {
    int acc = 0;
    for (int i = 0; i < nb; ++i) { int v = bsum[i]; bsum[i] = acc; acc += v; }
  }
}

__global__ __launch_bounds__(256) void scan3_k(int* off, const int* __restrict__ bsum) {
  int i = blockIdx.x * 256 + threadIdx.x;
  if (i < N_NODES) off[i] += bsum[i >> 10];
  if (i == 0) off[N_NODES] = N_EDGES;
}

// ---------------- CSR scatter ----------------
__global__ __launch_bounds__(256) void scatter_k(const int* __restrict__ ei, const float* __restrict__ ew,
                                                 const float* __restrict__ dinv, const int* __restrict__ off,
                                                 int* fill, int* crow, float* cnorm) {
  int e = blockIdx.x * 256 + threadIdx.x;
  if (e < N_EDGES) {
    int r = ei[e];
    int c = ei[N_EDGES + e];
    int pos = off[c] + atomicAdd(&fill[c], 1);
    crow[pos] = r;
    cnorm[pos] = dinv[r] * ew[e] * dinv[c];
  }
}

// ---------------- MFMA bf16 GEMM: Out[n,o] = sum_k A[n,k] * W[o,k] ----------------
// block = 256 thr (4 waves), 128 rows/block; each wave 32 rows x 128 cols.
// W (row-major [o][k], bf16) staged in LDS with XOR granule swizzle.
__global__ __launch_bounds__(256) void gemm_mfma_k(const unsigned short* __restrict__ A,
                                                   const unsigned short* __restrict__ W16,
                                                   unsigned short* __restrict__ Out) {
  __shared__ unsigned short Wl[128 * 128];
  int t = threadIdx.x;
  for (int idx = t; idx < 2048; idx += 256) {        // 128 rows x 16 granules of 8 bf16
    int n = idx >> 4, G = idx & 15;
    short8v v = *(const short8v*)(W16 + n * 128 + G * 8);
    int Gs = G ^ (n & 15);
    *(short8v*)(&Wl[n * 128 + Gs * 8]) = v;
  }
  __syncthreads();

  int wave = t >> 6, lane = t & 63;
  int l15 = lane & 15, l4 = lane >> 4;
  int rbase = blockIdx.x * 128 + wave * 32;

  float4v acc[2][8];
#pragma unroll
  for (int m = 0; m < 2; ++m)
#pragma unroll
    for (int f = 0; f < 8; ++f) acc[m][f] = (float4v){0.f, 0.f, 0.f, 0.f};

  int r0 = rbase + l15;        if (r0 >= N_NODES) r0 = N_NODES - 1;
  int r1 = rbase + 16 + l15;   if (r1 >= N_NODES) r1 = N_NODES - 1;

#pragma unroll
  for (int s = 0; s < 4; ++s) {
    int kk = s * 32 + l4 * 8;
    short8v a0 = *(const short8v*)(A + (size_t)r0 * 128 + kk);
    short8v a1 = *(const short8v*)(A + (size_t)r1 * 128 + kk);
#pragma unroll
    for (int f = 0; f < 8; ++f) {
      int n = f * 16 + l15;
      int G = s * 4 + l4;
      int Gs = G ^ (n & 15);
      short8v b = *(const short8v*)(&Wl[n * 128 + Gs * 8]);
      acc[0][f] = __builtin_amdgcn_mfma_f32_16x16x32_bf16(a0, b, acc[0][f], 0, 0, 0);
      acc[1][f] = __builtin_amdgcn_mfma_f32_16x16x32_bf16(a1, b, acc[1][f], 0, 0, 0);
    }
  }

#pragma unroll
  for (int m = 0; m < 2; ++m) {
    int rb = rbase + m * 16 + l4 * 4;
#pragma unroll
    for (int r = 0; r < 4; ++r) {
      int row = rb + r;
      if (row < N_NODES) {
        unsigned short* orow = Out + (size_t)row * 128 + l15;
#pragma unroll
        for (int f = 0; f < 8; ++f) orow[f * 16] = f2b(acc[m][f][r]);
      }
    }
  }
}

// ---------------- aggregate (bf16 gathers, fp32 accum): 1 wave per node ----------------
__global__ __launch_bounds__(64) void aggregate_k(const unsigned short* __restrict__ hw,
                                                  const float* __restrict__ dinv,
                                                  const int* __restrict__ off, const int* __restrict__ crow,
                                                  const float* __restrict__ cnorm, const float* __restrict__ bias,
                                                  unsigned short* __restrict__ hout) {
  int c = blockIdx.x, t = threadIdx.x;
  float di = dinv[c], d2 = di * di;
  unsigned int sv = *(const unsigned int*)(hw + (size_t)c * 128 + t * 2);
  float acc0 = d2 * blo(sv), acc1 = d2 * bhi(sv);
  int s = off[c], e = off[c + 1];
  int k = s;
  for (; k + 4 <= e; k += 4) {
    int r0 = crow[k], r1 = crow[k + 1], r2 = crow[k + 2], r3 = crow[k + 3];
    float w0 = cnorm[k], w1 = cnorm[k + 1], w2 = cnorm[k + 2], w3 = cnorm[k + 3];
    unsigned int v0 = *(const unsigned int*)(hw + (size_t)r0 * 128 + t * 2);
    unsigned int v1 = *(const unsigned int*)(hw + (size_t)r1 * 128 + t * 2);
    unsigned int v2 = *(const unsigned int*)(hw + (size_t)r2 * 128 + t * 2);
    unsigned int v3 = *(const unsigned int*)(hw + (size_t)r3 * 128 + t * 2);
    acc0 += w0 * blo(v0) + w1 * blo(v1) + w2 * blo(v2) + w3 * blo(v3);
    acc1 += w0 * bhi(v0) + w1 * bhi(v1) + w2 * bhi(v2) + w3 * bhi(v3);
  }
  for (; k < e; ++k) {
    int r = crow[k]; float w = cnorm[k];
    unsigned int v = *(const unsigned int*)(hw + (size_t)r * 128 + t * 2);
    acc0 += w * blo(v); acc1 += w * bhi(v);
  }
  acc0 += bias[t * 2];
  acc1 += bias[t * 2 + 1];
  acc0 = acc0 > 0.f ? acc0 : expm1f(acc0);
  acc1 = acc1 > 0.f ? acc1 : expm1f(acc1);
  unsigned int o = (unsigned int)f2b(acc0) | ((unsigned int)f2b(acc1) << 16);
  *(unsigned int*)(hout + (size_t)c * 128 + t * 2) = o;
}

// ---------------- mean-pool (sorted batch, run-length) ----------------
__global__ __launch_bounds__(64) void pool_k(const unsigned short* __restrict__ h, const int* __restrict__ batch,
                                             float* pool, int* cntG) {
  int t = threadIdx.x;
  const int nper = (N_NODES + gridDim.x - 1) / gridDim.x;
  int s = blockIdx.x * nper;
  int e = min(s + nper, N_NODES);
  if (s >= e) return;
  float a0 = 0.f, a1 = 0.f;
  int cur = batch[s], cnt = 0;
  for (int n = s; n < e; ++n) {
    int b = batch[n];
    if (b != cur) {
      atomicAdd(&pool[cur * HDIM + t * 2], a0);
      atomicAdd(&pool[cur * HDIM + t * 2 + 1], a1);
      if (t == 0) atomicAdd(&cntG[cur], cnt);
      a0 = a1 = 0.f; cnt = 0; cur = b;
    }
    unsigned int v = *(const unsigned int*)(h + (size_t)n * 128 + t * 2);
    a0 += blo(v); a1 += bhi(v); cnt++;
  }
  atomicAdd(&pool[cur * HDIM + t * 2], a0);
  atomicAdd(&pool[cur * HDIM + t * 2 + 1], a1);
  if (t == 0) atomicAdd(&cntG[cur], cnt);
}

// ---------------- head ----------------
__global__ __launch_bounds__(128) void head_k(const float* __restrict__ pool, const int* __restrict__ cntG,
                                              const float* __restrict__ fc1w, const float* __restrict__ fc1b,
                                              const float* __restrict__ fc2w, const float* __restrict__ fc2b,
                                              float* __restrict__ out) {
  __shared__ float p[HDIM];
  __shared__ float z1[HDIM];
  __shared__ float z2[NCLS];
  int g = blockIdx.x, t = threadIdx.x;
  float c = (float)max(cntG[g], 1);
  p[t] = pool[g * HDIM + t] / c;
  __syncthreads();
  float a = fc1b[t];
  for (int i = 0; i < HDIM; ++i) a += p[i] * fc1w[t * HDIM + i];
  z1[t] = (a > 0.f) ? a : expm1f(a);
  __syncthreads();
  if (t < NCLS) {
    float a2 = fc2b[t];
    for (int i = 0; i < HDIM; ++i) a2 += z1[i] * fc2w[t * HDIM + i];
    z2[t] = a2;
  }
  __syncthreads();
  if (t == 0) {
    float m = -1e30f;
    for (int i = 0; i < NCLS; ++i) m = fmaxf(m, z2[i]);
    float s2 = 0.f;
    for (int i = 0; i < NCLS; ++i) s2 += expf(z2[i] - m);
    float l = logf(s2);
    for (int i = 0; i < NCLS; ++i) out[g * NCLS + i] = z2[i] - m - l;
  }
}

// ---------------- launch ----------------
static inline size_t align256(size_t x) { return (x + 255) & ~(size_t)255; }

extern "C" void kernel_launch(void* const* d_in, const int* in_sizes, int n_in,
                              void* d_out, int out_size, void* d_ws, size_t ws_size,
                              hipStream_t stream) {
  const float* x     = (const float*)d_in[0];
  const int*   ei    = (const int*)d_in[1];
  const float* ew    = (const float*)d_in[2];
  const int*   batch = (const int*)d_in[3];
  const float* Wl[4] = { (const float*)d_in[4], (const float*)d_in[6], (const float*)d_in[8], (const float*)d_in[10] };
  const float* bl[4] = { (const float*)d_in[5], (const float*)d_in[7], (const float*)d_in[9], (const float*)d_in[11] };
  const float* fc1w = (const float*)d_in[12];
  const float* fc1b = (const float*)d_in[13];
  const float* fc2w = (const float*)d_in[14];
  const float* fc2b = (const float*)d_in[15];
  float* out = (float*)d_out;

  char* ws = (char*)d_ws;
  size_t o = 0;
  unsigned short* x16  = (unsigned short*)(ws + o); o = align256(o + (size_t)N_NODES * HDIM * 2);
  unsigned short* h16  = (unsigned short*)(ws + o); o = align256(o + (size_t)N_NODES * HDIM * 2);
  unsigned short* hw16 = (unsigned short*)(ws + o); o = align256(o + (size_t)N_NODES * HDIM * 2);
  unsigned short* w16[4];
  for (int l = 0; l < 4; ++l) { w16[l] = (unsigned short*)(ws + o); o = align256(o + (size_t)HDIM * HDIM * 2); }
  int*   crow  = (int*)  (ws + o); o = align256(o + (size_t)N_EDGES * 4);
  float* cnorm = (float*)(ws + o); o = align256(o + (size_t)N_EDGES * 4);
  float* deg   = (float*)(ws + o); o = align256(o + (size_t)N_NODES * 4);
  int*   cntN  = (int*)  (ws + o); o = align256(o + (size_t)N_NODES * 4);
  int*   off   = (int*)  (ws + o); o = align256(o + (size_t)(N_NODES + 1) * 4);
  int*   fill  = (int*)  (ws + o); o = align256(o + (size_t)N_NODES * 4);
  int*   bsum  = (int*)  (ws + o); o = align256(o + 4096);
  float* pool  = (float*)(ws + o); o = align256(o + (size_t)NGRAPH * HDIM * 4);
  int*   cntG  = (int*)  (ws + o); o = align256(o + (size_t)NGRAPH * 4);

  const int nscan = (N_NODES + 1023) / 1024;

  init_k<<<(NGRAPH * HDIM + 255) / 256, 256, 0, stream>>>(deg, cntN, fill, pool, cntG);
  cast4_k<<<(N_NODES * HDIM / 4 + 255) / 256, 256, 0, stream>>>(x, x16, N_NODES * HDIM / 4);
  for (int l = 0; l < 4; ++l)
    cast4_k<<<(HDIM * HDIM / 4 + 255) / 256, 256, 0, stream>>>(Wl[l], w16[l], HDIM * HDIM / 4);

  edge_deg_k<<<(N_EDGES + 255) / 256, 256, 0, stream>>>(ei, ew, deg, cntN);
  dinv_k<<<(N_NODES + 255) / 256, 256, 0, stream>>>(deg);
  scan1_k<<<nscan, 256, 0, stream>>>(cntN, off, bsum);
  scan2_k<<<1, 64, 0, stream>>>(bsum, nscan);
  scan3_k<<<(N_NODES + 255) / 256, 256, 0, stream>>>(off, bsum);
  scatter_k<<<(N_EDGES + 255) / 256, 256, 0, stream>>>(ei, ew, deg, off, fill, crow, cnorm);

  const unsigned short* hin = x16;
  for (int l = 0; l < 4; ++l) {
    gemm_mfma_k<<<(N_NODES + 127) / 128, 256, 0, stream>>>(hin, w16[l], hw16);
    aggregate_k<<<N_NODES, 64, 0, stream>>>(hw16, deg, off, crow, cnorm, bl[l], h16);
    hin = h16;
  }

  pool_k<<<256, 64, 0, stream>>>(h16, batch, pool, cntG);
  head_k<<<NGRAPH, 128, 0, stream>>>(pool, cntG, fc1w, fc1b, fc2w, fc2b, out);
}

// Round 5
// 494.280 us; speedup vs baseline: 2.4112x; 1.1906x over previous
//
#include <hip/hip_runtime.h>
#include <math.h>

#define N_NODES 50000
#define N_EDGES 1600000
#define HDIM 128
#define NGRAPH 512
#define NCLS 10

#define NPART 4
#define BINS 12500            // bins per part (NPART*BINS == N_NODES)
#define NSLICE 64
#define EDGES_PER_SLICE (N_EDGES / NSLICE)   // 25000

typedef __attribute__((ext_vector_type(8))) short short8v;
typedef __attribute__((ext_vector_type(4))) float float4v;

// bf16 helpers (packed pair in a uint: lo = feature 2t, hi = feature 2t+1)
__device__ inline float blo(unsigned int v) { return __uint_as_float(v << 16); }
__device__ inline float bhi(unsigned int v) { return __uint_as_float(v & 0xffff0000u); }
__device__ inline unsigned short f2b(float f) {
  unsigned int u = __float_as_uint(f);
  unsigned int r = u + 0x7fffu + ((u >> 16) & 1u);   // RNE
  return (unsigned short)(r >> 16);
}

// ---------------- init (pool accumulators only) ----------------
__global__ __launch_bounds__(256) void init_k(float* pool, int* cntG) {
  int i = blockIdx.x * 256 + threadIdx.x;
  if (i < NGRAPH * HDIM) pool[i] = 0.f;
  if (i < NGRAPH) cntG[i] = 0;
}

// ---------------- fp32 -> bf16 cast ----------------
__global__ __launch_bounds__(256) void cast4_k(const float* __restrict__ in, unsigned short* __restrict__ out, int n4) {
  int i = blockIdx.x * 256 + threadIdx.x;
  if (i < n4) {
    float4 v = ((const float4*)in)[i];
    ushort4 o;
    o.x = f2b(v.x); o.y = f2b(v.y); o.z = f2b(v.z); o.w = f2b(v.w);
    ((ushort4*)out)[i] = o;
  }
}

// ---------------- histogram + weighted degree, LDS only (no global atomics) ----------------
// grid = NPART*NSLICE blocks; block (p,b) counts targets in bin-part p over edge slice b.
__global__ __launch_bounds__(256) void hist_k(const int* __restrict__ ei, const float* __restrict__ ew,
                                              int* __restrict__ partialC, float* __restrict__ partialW) {
  __shared__ int cnt[BINS];
  __shared__ float wsum[BINS];
  int p = blockIdx.x >> 6;        // NSLICE == 64
  int b = blockIdx.x & 63;
  int t = threadIdx.x;
  for (int i = t; i < BINS; i += 256) { cnt[i] = 0; wsum[i] = 0.f; }
  __syncthreads();
  int lo = p * BINS;
  int s = b * EDGES_PER_SLICE;
  for (int i = t; i < EDGES_PER_SLICE; i += 256) {
    int c = ei[N_EDGES + s + i];
    int cl = c - lo;
    if ((unsigned)cl < (unsigned)BINS) {
      atomicAdd(&cnt[cl], 1);
      atomicAdd(&wsum[cl], ew[s + i]);
    }
  }
  __syncthreads();
  int* dc = partialC + (size_t)(p * NSLICE + b) * BINS;
  float* dw = partialW + (size_t)(p * NSLICE + b) * BINS;
  for (int i = t; i < BINS; i += 256) { dc[i] = cnt[i]; dw[i] = wsum[i]; }
}

// ---------------- per-bin prefix across slices + total count + dinv ----------------
__global__ __launch_bounds__(256) void seg_prefix_k(int* __restrict__ partialC, const float* __restrict__ partialW,
                                                    int* __restrict__ total, float* __restrict__ dinv) {
  int c = blockIdx.x * 256 + threadIdx.x;
  if (c >= N_NODES) return;
  int p = c / BINS, cl = c - p * BINS;
  int* base = partialC + (size_t)p * NSLICE * BINS + cl;
  const float* wb = partialW + (size_t)p * NSLICE * BINS + cl;
  int acc = 0;
  float wacc = 1.0f;     // self-loop weight
  for (int b = 0; b < NSLICE; ++b) {
    int v = base[(size_t)b * BINS];
    base[(size_t)b * BINS] = acc;
    acc += v;
    wacc += wb[(size_t)b * BINS];
  }
  total[c] = acc;
  dinv[c] = rsqrtf(wacc);
}

// ---------------- exclusive scan of total -> off ----------------
__global__ __launch_bounds__(256) void scan1_k(const int* __restrict__ cnt, int* off, int* bsum) {
  __shared__ int sdata[256];
  int t = threadIdx.x;
  int base = blockIdx.x * 1024 + t * 4;
  int v0 = (base + 0 < N_NODES) ? cnt[base + 0] : 0;
  int v1 = (base + 1 < N_NODES) ? cnt[base + 1] : 0;
  int v2 = (base + 2 < N_NODES) ? cnt[base + 2] : 0;
  int v3 = (base + 3 < N_NODES) ? cnt[base + 3] : 0;
  int s0 = v0, s1 = s0 + v1, s2 = s1 + v2, s3 = s2 + v3;
  sdata[t] = s3;
  __syncthreads();
  for (int d = 1; d < 256; d <<= 1) {
    int x = (t >= d) ? sdata[t - d] : 0;
    __syncthreads();
    sdata[t] += x;
    __syncthreads();
  }
  int excl = sdata[t] - s3;
  if (base + 0 < N_NODES) off[base + 0] = excl;
  if (base + 1 < N_NODES) off[base + 1] = excl + s0;
  if (base + 2 < N_NODES) off[base + 2] = excl + s1;
  if (base + 3 < N_NODES) off[base + 3] = excl + s2;
  if (t == 255) bsum[blockIdx.x] = sdata[255];
}

__global__ void scan2_k(int* bsum, int nb) {
  if (threadIdx.x == 0 && blockIdx.x == 0) {
    int acc = 0;
    for (int i = 0; i < nb; ++i) { int v = bsum[i]; bsum[i] = acc; acc += v; }
  }
}

__global__ __launch_bounds__(256) void scan3_k(int* off, const int* __restrict__ bsum) {
  int i = blockIdx.x * 256 + threadIdx.x;
  if (i < N_NODES) off[i] += bsum[i >> 10];
  if (i == 0) off[N_NODES] = N_EDGES;
}

// ---------------- CSR scatter via LDS rank (no global atomics) ----------------
__global__ __launch_bounds__(256) void scatter2_k(const int* __restrict__ ei, const float* __restrict__ ew,
                                                  const int* __restrict__ off, const int* __restrict__ partialC,
                                                  const float* __restrict__ dinv,
                                                  int* __restrict__ crow, float* __restrict__ cnorm) {
  __shared__ int cnt[BINS];
  int p = blockIdx.x >> 6;
  int b = blockIdx.x & 63;
  int t = threadIdx.x;
  for (int i = t; i < BINS; i += 256) cnt[i] = 0;
  __syncthreads();
  int lo = p * BINS;
  const int* base = partialC + (size_t)(p * NSLICE + b) * BINS;
  int s = b * EDGES_PER_SLICE;
  for (int i = t; i < EDGES_PER_SLICE; i += 256) {
    int c = ei[N_EDGES + s + i];
    int cl = c - lo;
    if ((unsigned)cl < (unsigned)BINS) {
      int rank = atomicAdd(&cnt[cl], 1);
      int pos = off[c] + base[cl] + rank;
      int r = ei[s + i];
      crow[pos] = r;
      cnorm[pos] = dinv[r] * ew[s + i] * dinv[c];
    }
  }
}

// ---------------- MFMA bf16 GEMM ----------------
__global__ __launch_bounds__(256) void gemm_mfma_k(const unsigned short* __restrict__ A,
                                                   const unsigned short* __restrict__ W16,
                                                   unsigned short* __restrict__ Out) {
  __shared__ unsigned short Wl[128 * 128];
  int t = threadIdx.x;
  for (int idx = t; idx < 2048; idx += 256) {
    int n = idx >> 4, G = idx & 15;
    short8v v = *(const short8v*)(W16 + n * 128 + G * 8);
    int Gs = G ^ (n & 15);
    *(short8v*)(&Wl[n * 128 + Gs * 8]) = v;
  }
  __syncthreads();

  int wave = t >> 6, lane = t & 63;
  int l15 = lane & 15, l4 = lane >> 4;
  int rbase = blockIdx.x * 128 + wave * 32;

  float4v acc[2][8];
#pragma unroll
  for (int m = 0; m < 2; ++m)
#pragma unroll
    for (int f = 0; f < 8; ++f) acc[m][f] = (float4v){0.f, 0.f, 0.f, 0.f};

  int r0 = rbase + l15;        if (r0 >= N_NODES) r0 = N_NODES - 1;
  int r1 = rbase + 16 + l15;   if (r1 >= N_NODES) r1 = N_NODES - 1;

#pragma unroll
  for (int s = 0; s < 4; ++s) {
    int kk = s * 32 + l4 * 8;
    short8v a0 = *(const short8v*)(A + (size_t)r0 * 128 + kk);
    short8v a1 = *(const short8v*)(A + (size_t)r1 * 128 + kk);
#pragma unroll
    for (int f = 0; f < 8; ++f) {
      int n = f * 16 + l15;
      int G = s * 4 + l4;
      int Gs = G ^ (n & 15);
      short8v bfr = *(const short8v*)(&Wl[n * 128 + Gs * 8]);
      acc[0][f] = __builtin_amdgcn_mfma_f32_16x16x32_bf16(a0, bfr, acc[0][f], 0, 0, 0);
      acc[1][f] = __builtin_amdgcn_mfma_f32_16x16x32_bf16(a1, bfr, acc[1][f], 0, 0, 0);
    }
  }

#pragma unroll
  for (int m = 0; m < 2; ++m) {
    int rb = rbase + m * 16 + l4 * 4;
#pragma unroll
    for (int r = 0; r < 4; ++r) {
      int row = rb + r;
      if (row < N_NODES) {
        unsigned short* orow = Out + (size_t)row * 128 + l15;
#pragma unroll
        for (int f = 0; f < 8; ++f) orow[f * 16] = f2b(acc[m][f][r]);
      }
    }
  }
}

// ---------------- aggregate (bf16 gathers, fp32 accum, unroll 8): 1 wave per node ----------------
__global__ __launch_bounds__(64) void aggregate_k(const unsigned short* __restrict__ hw,
                                                  const float* __restrict__ dinv,
                                                  const int* __restrict__ off, const int* __restrict__ crow,
                                                  const float* __restrict__ cnorm, const float* __restrict__ bias,
                                                  unsigned short* __restrict__ hout) {
  int c = blockIdx.x, t = threadIdx.x;
  float di = dinv[c], d2 = di * di;
  int col = t * 2;
  unsigned int sv = *(const unsigned int*)(hw + (size_t)c * 128 + col);
  float acc0 = d2 * blo(sv), acc1 = d2 * bhi(sv);
  int s = off[c], e = off[c + 1];
  int k = s;
  for (; k + 8 <= e; k += 8) {
    int r0 = crow[k], r1 = crow[k+1], r2 = crow[k+2], r3 = crow[k+3];
    int r4 = crow[k+4], r5 = crow[k+5], r6 = crow[k+6], r7 = crow[k+7];
    unsigned int v0 = *(const unsigned int*)(hw + (size_t)r0 * 128 + col);
    unsigned int v1 = *(const unsigned int*)(hw + (size_t)r1 * 128 + col);
    unsigned int v2 = *(const unsigned int*)(hw + (size_t)r2 * 128 + col);
    unsigned int v3 = *(const unsigned int*)(hw + (size_t)r3 * 128 + col);
    unsigned int v4 = *(const unsigned int*)(hw + (size_t)r4 * 128 + col);
    unsigned int v5 = *(const unsigned int*)(hw + (size_t)r5 * 128 + col);
    unsigned int v6 = *(const unsigned int*)(hw + (size_t)r6 * 128 + col);
    unsigned int v7 = *(const unsigned int*)(hw + (size_t)r7 * 128 + col);
    float w0 = cnorm[k], w1 = cnorm[k+1], w2 = cnorm[k+2], w3 = cnorm[k+3];
    float w4 = cnorm[k+4], w5 = cnorm[k+5], w6 = cnorm[k+6], w7 = cnorm[k+7];
    acc0 += w0 * blo(v0) + w1 * blo(v1) + w2 * blo(v2) + w3 * blo(v3);
    acc1 += w0 * bhi(v0) + w1 * bhi(v1) + w2 * bhi(v2) + w3 * bhi(v3);
    acc0 += w4 * blo(v4) + w5 * blo(v5) + w6 * blo(v6) + w7 * blo(v7);
    acc1 += w4 * bhi(v4) + w5 * bhi(v5) + w6 * bhi(v6) + w7 * bhi(v7);
  }
  for (; k < e; ++k) {
    int r = crow[k]; float w = cnorm[k];
    unsigned int v = *(const unsigned int*)(hw + (size_t)r * 128 + col);
    acc0 += w * blo(v); acc1 += w * bhi(v);
  }
  acc0 += bias[col];
  acc1 += bias[col + 1];
  acc0 = acc0 > 0.f ? acc0 : expm1f(acc0);
  acc1 = acc1 > 0.f ? acc1 : expm1f(acc1);
  unsigned int o = (unsigned int)f2b(acc0) | ((unsigned int)f2b(acc1) << 16);
  *(unsigned int*)(hout + (size_t)c * 128 + col) = o;
}

// ---------------- mean-pool (sorted batch, run-length) ----------------
__global__ __launch_bounds__(64) void pool_k(const unsigned short* __restrict__ h, const int* __restrict__ batch,
                                             float* pool, int* cntG) {
  int t = threadIdx.x;
  const int nper = (N_NODES + gridDim.x - 1) / gridDim.x;
  int s = blockIdx.x * nper;
  int e = min(s + nper, N_NODES);
  if (s >= e) return;
  float a0 = 0.f, a1 = 0.f;
  int cur = batch[s], cnt = 0;
  for (int n = s; n < e; ++n) {
    int b = batch[n];
    if (b != cur) {
      atomicAdd(&pool[cur * HDIM + t * 2], a0);
      atomicAdd(&pool[cur * HDIM + t * 2 + 1], a1);
      if (t == 0) atomicAdd(&cntG[cur], cnt);
      a0 = a1 = 0.f; cnt = 0; cur = b;
    }
    unsigned int v = *(const unsigned int*)(h + (size_t)n * 128 + t * 2);
    a0 += blo(v); a1 += bhi(v); cnt++;
  }
  atomicAdd(&pool[cur * HDIM + t * 2], a0);
  atomicAdd(&pool[cur * HDIM + t * 2 + 1], a1);
  if (t == 0) atomicAdd(&cntG[cur], cnt);
}

// ---------------- head ----------------
__global__ __launch_bounds__(128) void head_k(const float* __restrict__ pool, const int* __restrict__ cntG,
                                              const float* __restrict__ fc1w, const float* __restrict__ fc1b,
                                              const float* __restrict__ fc2w, const float* __restrict__ fc2b,
                                              float* __restrict__ out) {
  __shared__ float p[HDIM];
  __shared__ float z1[HDIM];
  __shared__ float z2[NCLS];
  int g = blockIdx.x, t = threadIdx.x;
  float c = (float)max(cntG[g], 1);
  p[t] = pool[g * HDIM + t] / c;
  __syncthreads();
  float a = fc1b[t];
  for (int i = 0; i < HDIM; ++i) a += p[i] * fc1w[t * HDIM + i];
  z1[t] = (a > 0.f) ? a : expm1f(a);
  __syncthreads();
  if (t < NCLS) {
    float a2 = fc2b[t];
    for (int i = 0; i < HDIM; ++i) a2 += z1[i] * fc2w[t * HDIM + i];
    z2[t] = a2;
  }
  __syncthreads();
  if (t == 0) {
    float m = -1e30f;
    for (int i = 0; i < NCLS; ++i) m = fmaxf(m, z2[i]);
    float s2 = 0.f;
    for (int i = 0; i < NCLS; ++i) s2 += expf(z2[i] - m);
    float l = logf(s2);
    for (int i = 0; i < NCLS; ++i) out[g * NCLS + i] = z2[i] - m - l;
  }
}

// ---------------- launch ----------------
static inline size_t align256(size_t x) { return (x + 255) & ~(size_t)255; }

extern "C" void kernel_launch(void* const* d_in, const int* in_sizes, int n_in,
                              void* d_out, int out_size, void* d_ws, size_t ws_size,
                              hipStream_t stream) {
  const float* x     = (const float*)d_in[0];
  const int*   ei    = (const int*)d_in[1];
  const float* ew    = (const float*)d_in[2];
  const int*   batch = (const int*)d_in[3];
  const float* Wl[4] = { (const float*)d_in[4], (const float*)d_in[6], (const float*)d_in[8], (const float*)d_in[10] };
  const float* bl[4] = { (const float*)d_in[5], (const float*)d_in[7], (const float*)d_in[9], (const float*)d_in[11] };
  const float* fc1w = (const float*)d_in[12];
  const float* fc1b = (const float*)d_in[13];
  const float* fc2w = (const float*)d_in[14];
  const float* fc2b = (const float*)d_in[15];
  float* out = (float*)d_out;

  char* ws = (char*)d_ws;
  size_t o = 0;
  unsigned short* x16  = (unsigned short*)(ws + o); o = align256(o + (size_t)N_NODES * HDIM * 2);
  unsigned short* h16  = (unsigned short*)(ws + o); o = align256(o + (size_t)N_NODES * HDIM * 2);
  // hw16 (12.8 MB) aliases partialC: partialC is live only hist_k..scatter2_k,
  // hw16 is first written by the first gemm_mfma_k (after scatter2_k). Keeps
  // peak workspace at the round-2-proven ~52 MB.
  unsigned short* hw16 = (unsigned short*)(ws + o);
  int* partialC        = (int*)(ws + o);            o = align256(o + (size_t)NPART * NSLICE * BINS * 4);
  unsigned short* w16[4];
  for (int l = 0; l < 4; ++l) { w16[l] = (unsigned short*)(ws + o); o = align256(o + (size_t)HDIM * HDIM * 2); }
  // partialW (12.8 MB) aliases crow+cnorm: partialW dead after seg_prefix_k,
  // crow/cnorm first written by scatter2_k.
  float* partialW = (float*)(ws + o);
  int*   crow     = (int*)(ws + o);   o = align256(o + (size_t)N_EDGES * 4);
  float* cnorm    = (float*)(ws + o); o = align256(o + (size_t)N_EDGES * 4);
  float* dinv  = (float*)(ws + o); o = align256(o + (size_t)N_NODES * 4);
  int*   total = (int*)  (ws + o); o = align256(o + (size_t)N_NODES * 4);
  int*   off   = (int*)  (ws + o); o = align256(o + (size_t)(N_NODES + 1) * 4);
  int*   bsum  = (int*)  (ws + o); o = align256(o + 4096);
  float* pool  = (float*)(ws + o); o = align256(o + (size_t)NGRAPH * HDIM * 4);
  int*   cntG  = (int*)  (ws + o); o = align256(o + (size_t)NGRAPH * 4);

  const int nscan = (N_NODES + 1023) / 1024;

  init_k<<<(NGRAPH * HDIM + 255) / 256, 256, 0, stream>>>(pool, cntG);
  cast4_k<<<(N_NODES * HDIM / 4 + 255) / 256, 256, 0, stream>>>(x, x16, N_NODES * HDIM / 4);
  for (int l = 0; l < 4; ++l)
    cast4_k<<<(HDIM * HDIM / 4 + 255) / 256, 256, 0, stream>>>(Wl[l], w16[l], HDIM * HDIM / 4);

  hist_k<<<NPART * NSLICE, 256, 0, stream>>>(ei, ew, partialC, partialW);
  seg_prefix_k<<<(N_NODES + 255) / 256, 256, 0, stream>>>(partialC, partialW, total, dinv);
  scan1_k<<<nscan, 256, 0, stream>>>(total, off, bsum);
  scan2_k<<<1, 64, 0, stream>>>(bsum, nscan);
  scan3_k<<<(N_NODES + 255) / 256, 256, 0, stream>>>(off, bsum);
  scatter2_k<<<NPART * NSLICE, 256, 0, stream>>>(ei, ew, off, partialC, dinv, crow, cnorm);

  const unsigned short* hin = x16;
  for (int l = 0; l < 4; ++l) {
    gemm_mfma_k<<<(N_NODES + 127) / 128, 256, 0, stream>>>(hin, w16[l], hw16);
    aggregate_k<<<N_NODES, 64, 0, stream>>>(hw16, dinv, off, crow, cnorm, bl[l], h16);
    hin = h16;
  }

  pool_k<<<256, 64, 0, stream>>>(h16, batch, pool, cntG);
  head_k<<<NGRAPH, 128, 0, stream>>>(pool, cntG, fc1w, fc1b, fc2w, fc2b, out);
}

// Round 6
// 443.201 us; speedup vs baseline: 2.6891x; 1.1152x over previous
//
#include <hip/hip_runtime.h>
#include <math.h>

#define N_NODES 50000
#define N_EDGES 1600000
#define HDIM 128
#define NGRAPH 512
#define NCLS 10

#define NSLICE 64
#define EDGES_PER_SLICE (N_EDGES / NSLICE)   // 25000
#define BSH 7                                 // bucket = node >> 7 (128 nodes/bucket)
#define NBUCK 391                             // ceil(N_NODES / 128)

typedef __attribute__((ext_vector_type(8))) short short8v;
typedef __attribute__((ext_vector_type(4))) float float4v;

// bf16 helpers (packed pair in a uint: lo = feature 2t, hi = feature 2t+1)
__device__ inline float blo(unsigned int v) { return __uint_as_float(v << 16); }
__device__ inline float bhi(unsigned int v) { return __uint_as_float(v & 0xffff0000u); }
__device__ inline unsigned short f2b(float f) {
  unsigned int u = __float_as_uint(f);
  unsigned int r = u + 0x7fffu + ((u >> 16) & 1u);   // RNE
  return (unsigned short)(r >> 16);
}

// ---------------- init (pool accumulators only) ----------------
__global__ __launch_bounds__(256) void init_k(float* pool, int* cntG) {
  int i = blockIdx.x * 256 + threadIdx.x;
  if (i < NGRAPH * HDIM) pool[i] = 0.f;
  if (i < NGRAPH) cntG[i] = 0;
}

// ---------------- fp32 -> bf16 cast ----------------
__global__ __launch_bounds__(256) void cast4_k(const float* __restrict__ in, unsigned short* __restrict__ out, int n4) {
  int i = blockIdx.x * 256 + threadIdx.x;
  if (i < n4) {
    float4 v = ((const float4*)in)[i];
    ushort4 o;
    o.x = f2b(v.x); o.y = f2b(v.y); o.z = f2b(v.z); o.w = f2b(v.w);
    ((ushort4*)out)[i] = o;
  }
}

// ---------------- phase A1: per-slice coarse-bucket histogram ----------------
__global__ __launch_bounds__(256) void countA_k(const int* __restrict__ ei, int* __restrict__ partialB) {
  __shared__ int cnt[NBUCK];
  int s = blockIdx.x, t = threadIdx.x;
  for (int i = t; i < NBUCK; i += 256) cnt[i] = 0;
  __syncthreads();
  int base = s * EDGES_PER_SLICE;
  for (int i = t; i < EDGES_PER_SLICE; i += 256) {
    int c = ei[N_EDGES + base + i];
    atomicAdd(&cnt[c >> BSH], 1);
  }
  __syncthreads();
  for (int i = t; i < NBUCK; i += 256) partialB[s * NBUCK + i] = cnt[i];
}

// ---------------- phase A2a: per-bucket exclusive prefix over slices ----------------
__global__ __launch_bounds__(256) void prefixA1_k(int* __restrict__ partialB, int* __restrict__ boff) {
  int b = blockIdx.x * 256 + threadIdx.x;
  if (b >= NBUCK) return;
  int acc = 0;
  for (int s = 0; s < NSLICE; ++s) {
    int v = partialB[s * NBUCK + b];
    partialB[s * NBUCK + b] = acc;
    acc += v;
  }
  boff[b] = acc;     // bucket total (scanned in prefixA2_k)
}

// ---------------- phase A2b: exclusive scan of bucket totals (1 block) ----------------
__global__ __launch_bounds__(512) void prefixA2_k(int* __restrict__ boff) {
  __shared__ int sd[512];
  int t = threadIdx.x;
  int my = (t < NBUCK) ? boff[t] : 0;
  sd[t] = my;
  __syncthreads();
  for (int d = 1; d < 512; d <<= 1) {
    int v = (t >= d) ? sd[t - d] : 0;
    __syncthreads();
    sd[t] += v;
    __syncthreads();
  }
  if (t < NBUCK) boff[t] = sd[t] - my;      // exclusive
  if (t == 511) boff[NBUCK] = sd[511];      // == N_EDGES
}

// ---------------- phase A3: scatter edges into coarse buckets (packed 8B) ----------------
// record: w(32) << 32 | r(16) << 7 | c_local(7)
__global__ __launch_bounds__(256) void bucketA_k(const int* __restrict__ ei, const float* __restrict__ ew,
                                                 const int* __restrict__ partialB, const int* __restrict__ boff,
                                                 unsigned long long* __restrict__ bucketed) {
  __shared__ int rnk[NBUCK];
  __shared__ int sbase[NBUCK];
  int s = blockIdx.x, t = threadIdx.x;
  for (int i = t; i < NBUCK; i += 256) { rnk[i] = 0; sbase[i] = boff[i] + partialB[s * NBUCK + i]; }
  __syncthreads();
  int base = s * EDGES_PER_SLICE;
  for (int i = t; i < EDGES_PER_SLICE; i += 256) {
    int c = ei[N_EDGES + base + i];
    int r = ei[base + i];
    float w = ew[base + i];
    int bk = c >> BSH;
    int rank = atomicAdd(&rnk[bk], 1);
    unsigned long long v = ((unsigned long long)__float_as_uint(w) << 32)
                         | ((unsigned long long)(unsigned)r << BSH)
                         | (unsigned long long)(c & 127);
    bucketed[(size_t)sbase[bk] + rank] = v;
  }
}

// ---------------- phase B1: per-bucket weighted degree -> dinv ----------------
__global__ __launch_bounds__(256) void degB_k(const unsigned long long* __restrict__ bucketed,
                                              const int* __restrict__ boff, float* __restrict__ dinv) {
  __shared__ float wsum[128];
  int b = blockIdx.x, t = threadIdx.x;
  if (t < 128) wsum[t] = 1.0f;    // self-loop weight
  __syncthreads();
  int s = boff[b], e = boff[b + 1];
  for (int i = s + t; i < e; i += 256) {
    unsigned long long v = bucketed[i];
    atomicAdd(&wsum[(int)(v & 127)], __uint_as_float((unsigned)(v >> 32)));
  }
  __syncthreads();
  int node = b * 128 + t;
  if (t < 128 && node < N_NODES) dinv[node] = rsqrtf(wsum[t]);
}

// ---------------- phase B2: per-bucket CSR build (block-exclusive output) ----------------
__global__ __launch_bounds__(256) void csrB_k(const unsigned long long* __restrict__ bucketed,
                                              const int* __restrict__ boff, const float* __restrict__ dinv,
                                              int* __restrict__ off, int* __restrict__ crow,
                                              float* __restrict__ cnorm) {
  __shared__ int cnt[128];
  __shared__ int sc[128];
  __shared__ int cnt2[128];
  __shared__ float dl[128];
  int b = blockIdx.x, t = threadIdx.x;
  if (t < 128) { cnt[t] = 0; cnt2[t] = 0; }
  __syncthreads();
  int s = boff[b], e = boff[b + 1];
  for (int i = s + t; i < e; i += 256)
    atomicAdd(&cnt[(int)(bucketed[i] & 127)], 1);
  __syncthreads();
  if (t < 128) sc[t] = cnt[t];
  __syncthreads();
  for (int d = 1; d < 128; d <<= 1) {
    int v = (t < 128 && t >= d) ? sc[t - d] : 0;
    __syncthreads();
    if (t < 128) sc[t] += v;
    __syncthreads();
  }
  // sc = inclusive prefix; exclusive = sc - cnt
  int node = b * 128 + t;
  if (t < 128 && node < N_NODES) {
    off[node] = s + sc[t] - cnt[t];
    dl[t] = dinv[node];
  }
  __syncthreads();
  for (int i = s + t; i < e; i += 256) {
    unsigned long long v = bucketed[i];
    int cl = (int)(v & 127);
    int r = (int)((v >> BSH) & 0xFFFF);
    float w = __uint_as_float((unsigned)(v >> 32));
    int rank = atomicAdd(&cnt2[cl], 1);
    int pos = s + sc[cl] - cnt[cl] + rank;
    crow[pos] = r;
    cnorm[pos] = dinv[r] * w * dl[cl];
  }
  if (b == 0 && t == 0) off[N_NODES] = N_EDGES;
}

// ---------------- MFMA bf16 GEMM ----------------
__global__ __launch_bounds__(256) void gemm_mfma_k(const unsigned short* __restrict__ A,
                                                   const unsigned short* __restrict__ W16,
                                                   unsigned short* __restrict__ Out) {
  __shared__ unsigned short Wl[128 * 128];
  int t = threadIdx.x;
  for (int idx = t; idx < 2048; idx += 256) {
    int n = idx >> 4, G = idx & 15;
    short8v v = *(const short8v*)(W16 + n * 128 + G * 8);
    int Gs = G ^ (n & 15);
    *(short8v*)(&Wl[n * 128 + Gs * 8]) = v;
  }
  __syncthreads();

  int wave = t >> 6, lane = t & 63;
  int l15 = lane & 15, l4 = lane >> 4;
  int rbase = blockIdx.x * 128 + wave * 32;

  float4v acc[2][8];
#pragma unroll
  for (int m = 0; m < 2; ++m)
#pragma unroll
    for (int f = 0; f < 8; ++f) acc[m][f] = (float4v){0.f, 0.f, 0.f, 0.f};

  int r0 = rbase + l15;        if (r0 >= N_NODES) r0 = N_NODES - 1;
  int r1 = rbase + 16 + l15;   if (r1 >= N_NODES) r1 = N_NODES - 1;

#pragma unroll
  for (int s = 0; s < 4; ++s) {
    int kk = s * 32 + l4 * 8;
    short8v a0 = *(const short8v*)(A + (size_t)r0 * 128 + kk);
    short8v a1 = *(const short8v*)(A + (size_t)r1 * 128 + kk);
#pragma unroll
    for (int f = 0; f < 8; ++f) {
      int n = f * 16 + l15;
      int G = s * 4 + l4;
      int Gs = G ^ (n & 15);
      short8v bfr = *(const short8v*)(&Wl[n * 128 + Gs * 8]);
      acc[0][f] = __builtin_amdgcn_mfma_f32_16x16x32_bf16(a0, bfr, acc[0][f], 0, 0, 0);
      acc[1][f] = __builtin_amdgcn_mfma_f32_16x16x32_bf16(a1, bfr, acc[1][f], 0, 0, 0);
    }
  }

#pragma unroll
  for (int m = 0; m < 2; ++m) {
    int rb = rbase + m * 16 + l4 * 4;
#pragma unroll
    for (int r = 0; r < 4; ++r) {
      int row = rb + r;
      if (row < N_NODES) {
        unsigned short* orow = Out + (size_t)row * 128 + l15;
#pragma unroll
        for (int f = 0; f < 8; ++f) orow[f * 16] = f2b(acc[m][f][r]);
      }
    }
  }
}

// ---------------- aggregate (bf16 gathers, fp32 accum, unroll 8): 1 wave per node ----------------
__global__ __launch_bounds__(64) void aggregate_k(const unsigned short* __restrict__ hw,
                                                  const float* __restrict__ dinv,
                                                  const int* __restrict__ off, const int* __restrict__ crow,
                                                  const float* __restrict__ cnorm, const float* __restrict__ bias,
                                                  unsigned short* __restrict__ hout) {
  int c = blockIdx.x, t = threadIdx.x;
  float di = dinv[c], d2 = di * di;
  int col = t * 2;
  unsigned int sv = *(const unsigned int*)(hw + (size_t)c * 128 + col);
  float acc0 = d2 * blo(sv), acc1 = d2 * bhi(sv);
  int s = off[c], e = off[c + 1];
  int k = s;
  for (; k + 8 <= e; k += 8) {
    int r0 = crow[k], r1 = crow[k+1], r2 = crow[k+2], r3 = crow[k+3];
    int r4 = crow[k+4], r5 = crow[k+5], r6 = crow[k+6], r7 = crow[k+7];
    unsigned int v0 = *(const unsigned int*)(hw + (size_t)r0 * 128 + col);
    unsigned int v1 = *(const unsigned int*)(hw + (size_t)r1 * 128 + col);
    unsigned int v2 = *(const unsigned int*)(hw + (size_t)r2 * 128 + col);
    unsigned int v3 = *(const unsigned int*)(hw + (size_t)r3 * 128 + col);
    unsigned int v4 = *(const unsigned int*)(hw + (size_t)r4 * 128 + col);
    unsigned int v5 = *(const unsigned int*)(hw + (size_t)r5 * 128 + col);
    unsigned int v6 = *(const unsigned int*)(hw + (size_t)r6 * 128 + col);
    unsigned int v7 = *(const unsigned int*)(hw + (size_t)r7 * 128 + col);
    float w0 = cnorm[k], w1 = cnorm[k+1], w2 = cnorm[k+2], w3 = cnorm[k+3];
    float w4 = cnorm[k+4], w5 = cnorm[k+5], w6 = cnorm[k+6], w7 = cnorm[k+7];
    acc0 += w0 * blo(v0) + w1 * blo(v1) + w2 * blo(v2) + w3 * blo(v3);
    acc1 += w0 * bhi(v0) + w1 * bhi(v1) + w2 * bhi(v2) + w3 * bhi(v3);
    acc0 += w4 * blo(v4) + w5 * blo(v5) + w6 * blo(v6) + w7 * blo(v7);
    acc1 += w4 * bhi(v4) + w5 * bhi(v5) + w6 * bhi(v6) + w7 * bhi(v7);
  }
  for (; k < e; ++k) {
    int r = crow[k]; float w = cnorm[k];
    unsigned int v = *(const unsigned int*)(hw + (size_t)r * 128 + col);
    acc0 += w * blo(v); acc1 += w * bhi(v);
  }
  acc0 += bias[col];
  acc1 += bias[col + 1];
  acc0 = acc0 > 0.f ? acc0 : expm1f(acc0);
  acc1 = acc1 > 0.f ? acc1 : expm1f(acc1);
  unsigned int o = (unsigned int)f2b(acc0) | ((unsigned int)f2b(acc1) << 16);
  *(unsigned int*)(hout + (size_t)c * 128 + col) = o;
}

// ---------------- mean-pool (sorted batch, run-length) ----------------
__global__ __launch_bounds__(64) void pool_k(const unsigned short* __restrict__ h, const int* __restrict__ batch,
                                             float* pool, int* cntG) {
  int t = threadIdx.x;
  const int nper = (N_NODES + gridDim.x - 1) / gridDim.x;
  int s = blockIdx.x * nper;
  int e = min(s + nper, N_NODES);
  if (s >= e) return;
  float a0 = 0.f, a1 = 0.f;
  int cur = batch[s], cnt = 0;
  for (int n = s; n < e; ++n) {
    int b = batch[n];
    if (b != cur) {
      atomicAdd(&pool[cur * HDIM + t * 2], a0);
      atomicAdd(&pool[cur * HDIM + t * 2 + 1], a1);
      if (t == 0) atomicAdd(&cntG[cur], cnt);
      a0 = a1 = 0.f; cnt = 0; cur = b;
    }
    unsigned int v = *(const unsigned int*)(h + (size_t)n * 128 + t * 2);
    a0 += blo(v); a1 += bhi(v); cnt++;
  }
  atomicAdd(&pool[cur * HDIM + t * 2], a0);
  atomicAdd(&pool[cur * HDIM + t * 2 + 1], a1);
  if (t == 0) atomicAdd(&cntG[cur], cnt);
}

// ---------------- head ----------------
__global__ __launch_bounds__(128) void head_k(const float* __restrict__ pool, const int* __restrict__ cntG,
                                              const float* __restrict__ fc1w, const float* __restrict__ fc1b,
                                              const float* __restrict__ fc2w, const float* __restrict__ fc2b,
                                              float* __restrict__ out) {
  __shared__ float p[HDIM];
  __shared__ float z1[HDIM];
  __shared__ float z2[NCLS];
  int g = blockIdx.x, t = threadIdx.x;
  float c = (float)max(cntG[g], 1);
  p[t] = pool[g * HDIM + t] / c;
  __syncthreads();
  float a = fc1b[t];
  for (int i = 0; i < HDIM; ++i) a += p[i] * fc1w[t * HDIM + i];
  z1[t] = (a > 0.f) ? a : expm1f(a);
  __syncthreads();
  if (t < NCLS) {
    float a2 = fc2b[t];
    for (int i = 0; i < HDIM; ++i) a2 += z1[i] * fc2w[t * HDIM + i];
    z2[t] = a2;
  }
  __syncthreads();
  if (t == 0) {
    float m = -1e30f;
    for (int i = 0; i < NCLS; ++i) m = fmaxf(m, z2[i]);
    float s2 = 0.f;
    for (int i = 0; i < NCLS; ++i) s2 += expf(z2[i] - m);
    float l = logf(s2);
    for (int i = 0; i < NCLS; ++i) out[g * NCLS + i] = z2[i] - m - l;
  }
}

// ---------------- launch ----------------
static inline size_t align256(size_t x) { return (x + 255) & ~(size_t)255; }

extern "C" void kernel_launch(void* const* d_in, const int* in_sizes, int n_in,
                              void* d_out, int out_size, void* d_ws, size_t ws_size,
                              hipStream_t stream) {
  const float* x     = (const float*)d_in[0];
  const int*   ei    = (const int*)d_in[1];
  const float* ew    = (const float*)d_in[2];
  const int*   batch = (const int*)d_in[3];
  const float* Wl[4] = { (const float*)d_in[4], (const float*)d_in[6], (const float*)d_in[8], (const float*)d_in[10] };
  const float* bl[4] = { (const float*)d_in[5], (const float*)d_in[7], (const float*)d_in[9], (const float*)d_in[11] };
  const float* fc1w = (const float*)d_in[12];
  const float* fc1b = (const float*)d_in[13];
  const float* fc2w = (const float*)d_in[14];
  const float* fc2b = (const float*)d_in[15];
  float* out = (float*)d_out;

  char* ws = (char*)d_ws;
  size_t o = 0;
  unsigned short* x16  = (unsigned short*)(ws + o); o = align256(o + (size_t)N_NODES * HDIM * 2);
  unsigned short* h16  = (unsigned short*)(ws + o); o = align256(o + (size_t)N_NODES * HDIM * 2);
  // bucketed (12.8 MB) aliases hw16: bucketed is dead after csrB_k; hw16 is
  // first written by the first gemm_mfma_k (launched after csrB_k).
  unsigned short* hw16 = (unsigned short*)(ws + o);
  unsigned long long* bucketed = (unsigned long long*)(ws + o);
  o = align256(o + (size_t)N_EDGES * 8);
  unsigned short* w16[4];
  for (int l = 0; l < 4; ++l) { w16[l] = (unsigned short*)(ws + o); o = align256(o + (size_t)HDIM * HDIM * 2); }
  int*   crow     = (int*)(ws + o);   o = align256(o + (size_t)N_EDGES * 4);
  float* cnorm    = (float*)(ws + o); o = align256(o + (size_t)N_EDGES * 4);
  int*   partialB = (int*)(ws + o);   o = align256(o + (size_t)NSLICE * NBUCK * 4);
  int*   boff     = (int*)(ws + o);   o = align256(o + (size_t)(NBUCK + 1) * 4);
  float* dinv  = (float*)(ws + o); o = align256(o + (size_t)N_NODES * 4);
  int*   off   = (int*)  (ws + o); o = align256(o + (size_t)(N_NODES + 1) * 4);
  float* pool  = (float*)(ws + o); o = align256(o + (size_t)NGRAPH * HDIM * 4);
  int*   cntG  = (int*)  (ws + o); o = align256(o + (size_t)NGRAPH * 4);

  init_k<<<(NGRAPH * HDIM + 255) / 256, 256, 0, stream>>>(pool, cntG);
  cast4_k<<<(N_NODES * HDIM / 4 + 255) / 256, 256, 0, stream>>>(x, x16, N_NODES * HDIM / 4);
  for (int l = 0; l < 4; ++l)
    cast4_k<<<(HDIM * HDIM / 4 + 255) / 256, 256, 0, stream>>>(Wl[l], w16[l], HDIM * HDIM / 4);

  countA_k<<<NSLICE, 256, 0, stream>>>(ei, partialB);
  prefixA1_k<<<(NBUCK + 255) / 256, 256, 0, stream>>>(partialB, boff);
  prefixA2_k<<<1, 512, 0, stream>>>(boff);
  bucketA_k<<<NSLICE, 256, 0, stream>>>(ei, ew, partialB, boff, bucketed);
  degB_k<<<NBUCK, 256, 0, stream>>>(bucketed, boff, dinv);
  csrB_k<<<NBUCK, 256, 0, stream>>>(bucketed, boff, dinv, off, crow, cnorm);

  const unsigned short* hin = x16;
  for (int l = 0; l < 4; ++l) {
    gemm_mfma_k<<<(N_NODES + 127) / 128, 256, 0, stream>>>(hin, w16[l], hw16);
    aggregate_k<<<N_NODES, 64, 0, stream>>>(hw16, dinv, off, crow, cnorm, bl[l], h16);
    hin = h16;
  }

  pool_k<<<256, 64, 0, stream>>>(h16, batch, pool, cntG);
  head_k<<<NGRAPH, 128, 0, stream>>>(pool, cntG, fc1w, fc1b, fc2w, fc2b, out);
}

// Round 7
// 411.827 us; speedup vs baseline: 2.8939x; 1.0762x over previous
//
#include <hip/hip_runtime.h>
#include <math.h>

#define N_NODES 50000
#define N_EDGES 1600000
#define HDIM 128
#define NGRAPH 512
#define NCLS 10

#define NSLICE 256
#define EDGES_PER_SLICE (N_EDGES / NSLICE)   // 6250
#define BSH 7                                 // bucket = node >> 7 (128 nodes/bucket)
#define NBUCK 391                             // ceil(N_NODES / 128)

typedef __attribute__((ext_vector_type(8))) short short8v;
typedef __attribute__((ext_vector_type(4))) float float4v;

// bf16 helpers (packed pair in a uint: lo = feature 2t, hi = feature 2t+1)
__device__ inline float blo(unsigned int v) { return __uint_as_float(v << 16); }
__device__ inline float bhi(unsigned int v) { return __uint_as_float(v & 0xffff0000u); }
__device__ inline float b2f(unsigned short u) { return __uint_as_float(((unsigned)u) << 16); }
__device__ inline unsigned short f2b(float f) {
  unsigned int u = __float_as_uint(f);
  unsigned int r = u + 0x7fffu + ((u >> 16) & 1u);   // RNE
  return (unsigned short)(r >> 16);
}

// ---------------- fp32 -> bf16 cast ----------------
__global__ __launch_bounds__(256) void cast4_k(const float* __restrict__ in, unsigned short* __restrict__ out, int n4) {
  int i = blockIdx.x * 256 + threadIdx.x;
  if (i < n4) {
    float4 v = ((const float4*)in)[i];
    ushort4 o;
    o.x = f2b(v.x); o.y = f2b(v.y); o.z = f2b(v.z); o.w = f2b(v.w);
    ((ushort4*)out)[i] = o;
  }
}

// ---------------- phase A1: per-slice coarse-bucket histogram ----------------
__global__ __launch_bounds__(256) void countA_k(const int* __restrict__ ei, int* __restrict__ partialB) {
  __shared__ int cnt[NBUCK];
  int s = blockIdx.x, t = threadIdx.x;
  for (int i = t; i < NBUCK; i += 256) cnt[i] = 0;
  __syncthreads();
  int base = s * EDGES_PER_SLICE;
  for (int i = t; i < EDGES_PER_SLICE; i += 256) {
    int c = ei[N_EDGES + base + i];
    atomicAdd(&cnt[c >> BSH], 1);
  }
  __syncthreads();
  for (int i = t; i < NBUCK; i += 256) partialB[s * NBUCK + i] = cnt[i];
}

// ---------------- phase A2a: per-bucket exclusive prefix over slices ----------------
__global__ __launch_bounds__(256) void prefixA1_k(int* __restrict__ partialB, int* __restrict__ boff) {
  int b = blockIdx.x * 256 + threadIdx.x;
  if (b >= NBUCK) return;
  int acc = 0;
  for (int s = 0; s < NSLICE; ++s) {
    int v = partialB[s * NBUCK + b];
    partialB[s * NBUCK + b] = acc;
    acc += v;
  }
  boff[b] = acc;     // bucket total (scanned in prefixA2_k)
}

// ---------------- phase A2b: exclusive scan of bucket totals (1 block) ----------------
__global__ __launch_bounds__(512) void prefixA2_k(int* __restrict__ boff) {
  __shared__ int sd[512];
  int t = threadIdx.x;
  int my = (t < NBUCK) ? boff[t] : 0;
  sd[t] = my;
  __syncthreads();
  for (int d = 1; d < 512; d <<= 1) {
    int v = (t >= d) ? sd[t - d] : 0;
    __syncthreads();
    sd[t] += v;
    __syncthreads();
  }
  if (t < NBUCK) boff[t] = sd[t] - my;      // exclusive
  if (t == 511) boff[NBUCK] = sd[511];      // == N_EDGES
}

// ---------------- phase A3: scatter edges into coarse buckets (packed 8B) ----------------
// record: w(32) << 32 | r(16) << 7 | c_local(7)
__global__ __launch_bounds__(256) void bucketA_k(const int* __restrict__ ei, const float* __restrict__ ew,
                                                 const int* __restrict__ partialB, const int* __restrict__ boff,
                                                 unsigned long long* __restrict__ bucketed) {
  __shared__ int rnk[NBUCK];
  __shared__ int sbase[NBUCK];
  int s = blockIdx.x, t = threadIdx.x;
  for (int i = t; i < NBUCK; i += 256) { rnk[i] = 0; sbase[i] = boff[i] + partialB[s * NBUCK + i]; }
  __syncthreads();
  int base = s * EDGES_PER_SLICE;
  for (int i = t; i < EDGES_PER_SLICE; i += 256) {
    int c = ei[N_EDGES + base + i];
    int r = ei[base + i];
    float w = ew[base + i];
    int bk = c >> BSH;
    int rank = atomicAdd(&rnk[bk], 1);
    unsigned long long v = ((unsigned long long)__float_as_uint(w) << 32)
                         | ((unsigned long long)(unsigned)r << BSH)
                         | (unsigned long long)(c & 127);
    bucketed[(size_t)sbase[bk] + rank] = v;
  }
}

// ---------------- phase B1: per-bucket weighted degree -> dinv ----------------
__global__ __launch_bounds__(256) void degB_k(const unsigned long long* __restrict__ bucketed,
                                              const int* __restrict__ boff, float* __restrict__ dinv) {
  __shared__ float wsum[128];
  int b = blockIdx.x, t = threadIdx.x;
  if (t < 128) wsum[t] = 1.0f;    // self-loop weight
  __syncthreads();
  int s = boff[b], e = boff[b + 1];
  for (int i = s + t; i < e; i += 256) {
    unsigned long long v = bucketed[i];
    atomicAdd(&wsum[(int)(v & 127)], __uint_as_float((unsigned)(v >> 32)));
  }
  __syncthreads();
  int node = b * 128 + t;
  if (t < 128 && node < N_NODES) dinv[node] = rsqrtf(wsum[t]);
}

// ---------------- phase B2: per-bucket CSR build (block-exclusive output) ----------------
__global__ __launch_bounds__(256) void csrB_k(const unsigned long long* __restrict__ bucketed,
                                              const int* __restrict__ boff, const float* __restrict__ dinv,
                                              int* __restrict__ off, int* __restrict__ crow,
                                              float* __restrict__ cnorm) {
  __shared__ int cnt[128];
  __shared__ int sc[128];
  __shared__ int cnt2[128];
  __shared__ float dl[128];
  int b = blockIdx.x, t = threadIdx.x;
  if (t < 128) { cnt[t] = 0; cnt2[t] = 0; }
  __syncthreads();
  int s = boff[b], e = boff[b + 1];
  for (int i = s + t; i < e; i += 256)
    atomicAdd(&cnt[(int)(bucketed[i] & 127)], 1);
  __syncthreads();
  if (t < 128) sc[t] = cnt[t];
  __syncthreads();
  for (int d = 1; d < 128; d <<= 1) {
    int v = (t < 128 && t >= d) ? sc[t - d] : 0;
    __syncthreads();
    if (t < 128) sc[t] += v;
    __syncthreads();
  }
  // sc = inclusive prefix; exclusive = sc - cnt
  int node = b * 128 + t;
  if (t < 128 && node < N_NODES) {
    off[node] = s + sc[t] - cnt[t];
    dl[t] = dinv[node];
  }
  __syncthreads();
  for (int i = s + t; i < e; i += 256) {
    unsigned long long v = bucketed[i];
    int cl = (int)(v & 127);
    int r = (int)((v >> BSH) & 0xFFFF);
    float w = __uint_as_float((unsigned)(v >> 32));
    int rank = atomicAdd(&cnt2[cl], 1);
    int pos = s + sc[cl] - cnt[cl] + rank;
    crow[pos] = r;
    cnorm[pos] = dinv[r] * w * dl[cl];
  }
  if (b == 0 && t == 0) off[N_NODES] = N_EDGES;
}

// ---------------- MFMA bf16 GEMM ----------------
__global__ __launch_bounds__(256) void gemm_mfma_k(const unsigned short* __restrict__ A,
                                                   const unsigned short* __restrict__ W16,
                                                   unsigned short* __restrict__ Out) {
  __shared__ unsigned short Wl[128 * 128];
  int t = threadIdx.x;
  for (int idx = t; idx < 2048; idx += 256) {
    int n = idx >> 4, G = idx & 15;
    short8v v = *(const short8v*)(W16 + n * 128 + G * 8);
    int Gs = G ^ (n & 15);
    *(short8v*)(&Wl[n * 128 + Gs * 8]) = v;
  }
  __syncthreads();

  int wave = t >> 6, lane = t & 63;
  int l15 = lane & 15, l4 = lane >> 4;
  int rbase = blockIdx.x * 128 + wave * 32;

  float4v acc[2][8];
#pragma unroll
  for (int m = 0; m < 2; ++m)
#pragma unroll
    for (int f = 0; f < 8; ++f) acc[m][f] = (float4v){0.f, 0.f, 0.f, 0.f};

  int r0 = rbase + l15;        if (r0 >= N_NODES) r0 = N_NODES - 1;
  int r1 = rbase + 16 + l15;   if (r1 >= N_NODES) r1 = N_NODES - 1;

#pragma unroll
  for (int s = 0; s < 4; ++s) {
    int kk = s * 32 + l4 * 8;
    short8v a0 = *(const short8v*)(A + (size_t)r0 * 128 + kk);
    short8v a1 = *(const short8v*)(A + (size_t)r1 * 128 + kk);
#pragma unroll
    for (int f = 0; f < 8; ++f) {
      int n = f * 16 + l15;
      int G = s * 4 + l4;
      int Gs = G ^ (n & 15);
      short8v bfr = *(const short8v*)(&Wl[n * 128 + Gs * 8]);
      acc[0][f] = __builtin_amdgcn_mfma_f32_16x16x32_bf16(a0, bfr, acc[0][f], 0, 0, 0);
      acc[1][f] = __builtin_amdgcn_mfma_f32_16x16x32_bf16(a1, bfr, acc[1][f], 0, 0, 0);
    }
  }

#pragma unroll
  for (int m = 0; m < 2; ++m) {
    int rb = rbase + m * 16 + l4 * 4;
#pragma unroll
    for (int r = 0; r < 4; ++r) {
      int row = rb + r;
      if (row < N_NODES) {
        unsigned short* orow = Out + (size_t)row * 128 + l15;
#pragma unroll
        for (int f = 0; f < 8; ++f) orow[f * 16] = f2b(acc[m][f][r]);
      }
    }
  }
}

// ---------------- aggregate: 1 node per wave, 4 waves per block ----------------
__global__ __launch_bounds__(256) void aggregate_k(const unsigned short* __restrict__ hw,
                                                   const float* __restrict__ dinv,
                                                   const int* __restrict__ off, const int* __restrict__ crow,
                                                   const float* __restrict__ cnorm, const float* __restrict__ bias,
                                                   unsigned short* __restrict__ hout) {
  int c = blockIdx.x * 4 + (threadIdx.x >> 6);
  if (c >= N_NODES) return;
  int t = threadIdx.x & 63;
  float di = dinv[c], d2 = di * di;
  int col = t * 2;
  unsigned int sv = *(const unsigned int*)(hw + (size_t)c * 128 + col);
  float acc0 = d2 * blo(sv), acc1 = d2 * bhi(sv);
  int s = off[c], e = off[c + 1];
  int k = s;
  for (; k + 8 <= e; k += 8) {
    int r0 = crow[k], r1 = crow[k+1], r2 = crow[k+2], r3 = crow[k+3];
    int r4 = crow[k+4], r5 = crow[k+5], r6 = crow[k+6], r7 = crow[k+7];
    unsigned int v0 = *(const unsigned int*)(hw + (size_t)r0 * 128 + col);
    unsigned int v1 = *(const unsigned int*)(hw + (size_t)r1 * 128 + col);
    unsigned int v2 = *(const unsigned int*)(hw + (size_t)r2 * 128 + col);
    unsigned int v3 = *(const unsigned int*)(hw + (size_t)r3 * 128 + col);
    unsigned int v4 = *(const unsigned int*)(hw + (size_t)r4 * 128 + col);
    unsigned int v5 = *(const unsigned int*)(hw + (size_t)r5 * 128 + col);
    unsigned int v6 = *(const unsigned int*)(hw + (size_t)r6 * 128 + col);
    unsigned int v7 = *(const unsigned int*)(hw + (size_t)r7 * 128 + col);
    float w0 = cnorm[k], w1 = cnorm[k+1], w2 = cnorm[k+2], w3 = cnorm[k+3];
    float w4 = cnorm[k+4], w5 = cnorm[k+5], w6 = cnorm[k+6], w7 = cnorm[k+7];
    acc0 += w0 * blo(v0) + w1 * blo(v1) + w2 * blo(v2) + w3 * blo(v3);
    acc1 += w0 * bhi(v0) + w1 * bhi(v1) + w2 * bhi(v2) + w3 * bhi(v3);
    acc0 += w4 * blo(v4) + w5 * blo(v5) + w6 * blo(v6) + w7 * blo(v7);
    acc1 += w4 * bhi(v4) + w5 * bhi(v5) + w6 * bhi(v6) + w7 * bhi(v7);
  }
  for (; k < e; ++k) {
    int r = crow[k]; float w = cnorm[k];
    unsigned int v = *(const unsigned int*)(hw + (size_t)r * 128 + col);
    acc0 += w * blo(v); acc1 += w * bhi(v);
  }
  acc0 += bias[col];
  acc1 += bias[col + 1];
  acc0 = acc0 > 0.f ? acc0 : expm1f(acc0);
  acc1 = acc1 > 0.f ? acc1 : expm1f(acc1);
  unsigned int o = (unsigned int)f2b(acc0) | ((unsigned int)f2b(acc1) << 16);
  *(unsigned int*)(hout + (size_t)c * 128 + col) = o;
}

// ---------------- fused mean-pool + head (batch sorted -> binary search range) ----------------
__global__ __launch_bounds__(128) void poolhead_k(const unsigned short* __restrict__ h,
                                                  const int* __restrict__ batch,
                                                  const float* __restrict__ fc1w, const float* __restrict__ fc1b,
                                                  const float* __restrict__ fc2w, const float* __restrict__ fc2b,
                                                  float* __restrict__ out) {
  __shared__ float ps[HDIM];
  __shared__ float z1[HDIM];
  __shared__ float z2[NCLS];
  int g = blockIdx.x, t = threadIdx.x;
  // lower_bound(batch, g) and lower_bound(batch, g+1) — uniform across threads
  int lo = 0, hi = N_NODES;
  while (lo < hi) { int mid = (lo + hi) >> 1; if (batch[mid] < g) lo = mid + 1; else hi = mid; }
  int gs = lo;
  hi = N_NODES;
  while (lo < hi) { int mid = (lo + hi) >> 1; if (batch[mid] < g + 1) lo = mid + 1; else hi = mid; }
  int ge = lo;
  float a = 0.f;
  for (int n = gs; n < ge; ++n) a += b2f(h[(size_t)n * 128 + t]);
  ps[t] = a / (float)max(ge - gs, 1);
  __syncthreads();
  float acc = fc1b[t];
  for (int i = 0; i < HDIM; ++i) acc += ps[i] * fc1w[t * HDIM + i];
  z1[t] = (acc > 0.f) ? acc : expm1f(acc);
  __syncthreads();
  if (t < NCLS) {
    float a2 = fc2b[t];
    for (int i = 0; i < HDIM; ++i) a2 += z1[i] * fc2w[t * HDIM + i];
    z2[t] = a2;
  }
  __syncthreads();
  if (t == 0) {
    float m = -1e30f;
    for (int i = 0; i < NCLS; ++i) m = fmaxf(m, z2[i]);
    float s2 = 0.f;
    for (int i = 0; i < NCLS; ++i) s2 += expf(z2[i] - m);
    float l = logf(s2);
    for (int i = 0; i < NCLS; ++i) out[g * NCLS + i] = z2[i] - m - l;
  }
}

// ---------------- launch ----------------
static inline size_t align256(size_t x) { return (x + 255) & ~(size_t)255; }

extern "C" void kernel_launch(void* const* d_in, const int* in_sizes, int n_in,
                              void* d_out, int out_size, void* d_ws, size_t ws_size,
                              hipStream_t stream) {
  const float* x     = (const float*)d_in[0];
  const int*   ei    = (const int*)d_in[1];
  const float* ew    = (const float*)d_in[2];
  const int*   batch = (const int*)d_in[3];
  const float* Wl[4] = { (const float*)d_in[4], (const float*)d_in[6], (const float*)d_in[8], (const float*)d_in[10] };
  const float* bl[4] = { (const float*)d_in[5], (const float*)d_in[7], (const float*)d_in[9], (const float*)d_in[11] };
  const float* fc1w = (const float*)d_in[12];
  const float* fc1b = (const float*)d_in[13];
  const float* fc2w = (const float*)d_in[14];
  const float* fc2b = (const float*)d_in[15];
  float* out = (float*)d_out;

  char* ws = (char*)d_ws;
  size_t o = 0;
  unsigned short* x16  = (unsigned short*)(ws + o); o = align256(o + (size_t)N_NODES * HDIM * 2);
  unsigned short* h16  = (unsigned short*)(ws + o); o = align256(o + (size_t)N_NODES * HDIM * 2);
  // bucketed (12.8 MB) aliases hw16: bucketed dead after csrB_k; hw16 first
  // written by the first gemm_mfma_k (launched after csrB_k).
  unsigned short* hw16 = (unsigned short*)(ws + o);
  unsigned long long* bucketed = (unsigned long long*)(ws + o);
  o = align256(o + (size_t)N_EDGES * 8);
  unsigned short* w16[4];
  for (int l = 0; l < 4; ++l) { w16[l] = (unsigned short*)(ws + o); o = align256(o + (size_t)HDIM * HDIM * 2); }
  int*   crow     = (int*)(ws + o);   o = align256(o + (size_t)N_EDGES * 4);
  float* cnorm    = (float*)(ws + o); o = align256(o + (size_t)N_EDGES * 4);
  int*   partialB = (int*)(ws + o);   o = align256(o + (size_t)NSLICE * NBUCK * 4);
  int*   boff     = (int*)(ws + o);   o = align256(o + (size_t)(NBUCK + 1) * 4);
  float* dinv  = (float*)(ws + o); o = align256(o + (size_t)N_NODES * 4);
  int*   off   = (int*)  (ws + o); o = align256(o + (size_t)(N_NODES + 1) * 4);

  cast4_k<<<(N_NODES * HDIM / 4 + 255) / 256, 256, 0, stream>>>(x, x16, N_NODES * HDIM / 4);
  for (int l = 0; l < 4; ++l)
    cast4_k<<<(HDIM * HDIM / 4 + 255) / 256, 256, 0, stream>>>(Wl[l], w16[l], HDIM * HDIM / 4);

  countA_k<<<NSLICE, 256, 0, stream>>>(ei, partialB);
  prefixA1_k<<<(NBUCK + 255) / 256, 256, 0, stream>>>(partialB, boff);
  prefixA2_k<<<1, 512, 0, stream>>>(boff);
  bucketA_k<<<NSLICE, 256, 0, stream>>>(ei, ew, partialB, boff, bucketed);
  degB_k<<<NBUCK, 256, 0, stream>>>(bucketed, boff, dinv);
  csrB_k<<<NBUCK, 256, 0, stream>>>(bucketed, boff, dinv, off, crow, cnorm);

  const unsigned short* hin = x16;
  for (int l = 0; l < 4; ++l) {
    gemm_mfma_k<<<(N_NODES + 127) / 128, 256, 0, stream>>>(hin, w16[l], hw16);
    aggregate_k<<<(N_NODES + 3) / 4, 256, 0, stream>>>(hw16, dinv, off, crow, cnorm, bl[l], h16);
    hin = h16;
  }

  poolhead_k<<<NGRAPH, 128, 0, stream>>>(h16, batch, fc1w, fc1b, fc2w, fc2b, out);
}

// Round 8
// 348.148 us; speedup vs baseline: 3.4232x; 1.1829x over previous
//
#include <hip/hip_runtime.h>
#include <math.h>

#define N_NODES 50000
#define N_EDGES 1600000
#define HDIM 128
#define NGRAPH 512
#define NCLS 10

#define NSLICE 256
#define EDGES_PER_SLICE (N_EDGES / NSLICE)   // 6250
#define BSH 7                                 // bucket = node >> 7 (128 nodes/bucket)
#define NBUCK 391                             // ceil(N_NODES / 128)

typedef __attribute__((ext_vector_type(8))) short short8v;
typedef __attribute__((ext_vector_type(4))) float float4v;
typedef __attribute__((ext_vector_type(2))) float float2v;

// bf16 helpers
__device__ inline float blo(unsigned int v) { return __uint_as_float(v << 16); }
__device__ inline float bhi(unsigned int v) { return __uint_as_float(v & 0xffff0000u); }
__device__ inline float b2f(unsigned short u) { return __uint_as_float(((unsigned)u) << 16); }
__device__ inline unsigned short f2b(float f) {
  unsigned int u = __float_as_uint(f);
  unsigned int r = u + 0x7fffu + ((u >> 16) & 1u);   // RNE
  return (unsigned short)(r >> 16);
}
// fp8 e4m3 (OCP) hardware converts
__device__ inline unsigned char f2fp8(float f) {
  return (unsigned char)(__builtin_amdgcn_cvt_pk_fp8_f32(f, 0.f, 0, false) & 0xFF);
}
__device__ inline float2v fp8x2_2f(unsigned int u) {
  return __builtin_amdgcn_cvt_pk_f32_fp8(u, false);   // decodes bytes 0,1
}

// ---------------- fp32 -> bf16 cast ----------------
__global__ __launch_bounds__(256) void cast4_k(const float* __restrict__ in, unsigned short* __restrict__ out, int n4) {
  int i = blockIdx.x * 256 + threadIdx.x;
  if (i < n4) {
    float4 v = ((const float4*)in)[i];
    ushort4 o;
    o.x = f2b(v.x); o.y = f2b(v.y); o.z = f2b(v.z); o.w = f2b(v.w);
    ((ushort4*)out)[i] = o;
  }
}

// all 4 layer weights in one launch (4 x 16384 fp32, 4 elems/thread)
__global__ __launch_bounds__(256) void castw_k(const float* __restrict__ w0, const float* __restrict__ w1,
                                               const float* __restrict__ w2, const float* __restrict__ w3,
                                               unsigned short* __restrict__ o0, unsigned short* __restrict__ o1,
                                               unsigned short* __restrict__ o2, unsigned short* __restrict__ o3) {
  int i = blockIdx.x * 256 + threadIdx.x;         // 0 .. 16383
  int l = i >> 12, j = i & 4095;                  // 4096 float4 per weight
  const float* in = (l == 0) ? w0 : (l == 1) ? w1 : (l == 2) ? w2 : w3;
  unsigned short* out = (l == 0) ? o0 : (l == 1) ? o1 : (l == 2) ? o2 : o3;
  float4 v = ((const float4*)in)[j];
  ushort4 o;
  o.x = f2b(v.x); o.y = f2b(v.y); o.z = f2b(v.z); o.w = f2b(v.w);
  ((ushort4*)out)[j] = o;
}

// ---------------- phase A1: per-slice coarse-bucket histogram ----------------
__global__ __launch_bounds__(256) void countA_k(const int* __restrict__ ei, int* __restrict__ partialB) {
  __shared__ int cnt[NBUCK];
  int s = blockIdx.x, t = threadIdx.x;
  for (int i = t; i < NBUCK; i += 256) cnt[i] = 0;
  __syncthreads();
  int base = s * EDGES_PER_SLICE;
  for (int i = t; i < EDGES_PER_SLICE; i += 256) {
    int c = ei[N_EDGES + base + i];
    atomicAdd(&cnt[c >> BSH], 1);
  }
  __syncthreads();
  for (int i = t; i < NBUCK; i += 256) partialB[s * NBUCK + i] = cnt[i];
}

// ---------------- phase A2a: per-bucket exclusive prefix over slices ----------------
__global__ __launch_bounds__(256) void prefixA1_k(int* __restrict__ partialB, int* __restrict__ boff) {
  int b = blockIdx.x * 256 + threadIdx.x;
  if (b >= NBUCK) return;
  int acc = 0;
  for (int s = 0; s < NSLICE; ++s) {
    int v = partialB[s * NBUCK + b];
    partialB[s * NBUCK + b] = acc;
    acc += v;
  }
  boff[b] = acc;
}

// ---------------- phase A2b: exclusive scan of bucket totals (1 block) ----------------
__global__ __launch_bounds__(512) void prefixA2_k(int* __restrict__ boff) {
  __shared__ int sd[512];
  int t = threadIdx.x;
  int my = (t < NBUCK) ? boff[t] : 0;
  sd[t] = my;
  __syncthreads();
  for (int d = 1; d < 512; d <<= 1) {
    int v = (t >= d) ? sd[t - d] : 0;
    __syncthreads();
    sd[t] += v;
    __syncthreads();
  }
  if (t < NBUCK) boff[t] = sd[t] - my;
  if (t == 511) boff[NBUCK] = sd[511];
}

// ---------------- phase A3: scatter edges into coarse buckets (packed 8B) ----------------
// record: w(32) << 32 | r(16) << 7 | c_local(7)
__global__ __launch_bounds__(256) void bucketA_k(const int* __restrict__ ei, const float* __restrict__ ew,
                                                 const int* __restrict__ partialB, const int* __restrict__ boff,
                                                 unsigned long long* __restrict__ bucketed) {
  __shared__ int rnk[NBUCK];
  __shared__ int sbase[NBUCK];
  int s = blockIdx.x, t = threadIdx.x;
  for (int i = t; i < NBUCK; i += 256) { rnk[i] = 0; sbase[i] = boff[i] + partialB[s * NBUCK + i]; }
  __syncthreads();
  int base = s * EDGES_PER_SLICE;
  for (int i = t; i < EDGES_PER_SLICE; i += 256) {
    int c = ei[N_EDGES + base + i];
    int r = ei[base + i];
    float w = ew[base + i];
    int bk = c >> BSH;
    int rank = atomicAdd(&rnk[bk], 1);
    unsigned long long v = ((unsigned long long)__float_as_uint(w) << 32)
                         | ((unsigned long long)(unsigned)r << BSH)
                         | (unsigned long long)(c & 127);
    bucketed[(size_t)sbase[bk] + rank] = v;
  }
}

// ---------------- phase B: per-bucket degree + CSR build (fused, block-exclusive) ----------------
// cpack = bf16(w)<<16 | r   (dinv folded into rows / applied at aggregate)
__global__ __launch_bounds__(256) void csrB_k(const unsigned long long* __restrict__ bucketed,
                                              const int* __restrict__ boff,
                                              int* __restrict__ off, float* __restrict__ dinv,
                                              unsigned int* __restrict__ cpack) {
  __shared__ int cnt[128];
  __shared__ float wsum[128];
  __shared__ int sc[128];
  __shared__ int cnt2[128];
  int b = blockIdx.x, t = threadIdx.x;
  if (t < 128) { cnt[t] = 0; cnt2[t] = 0; wsum[t] = 1.0f; }   // self-loop weight
  __syncthreads();
  int s = boff[b], e = boff[b + 1];
  for (int i = s + t; i < e; i += 256) {
    unsigned long long v = bucketed[i];
    atomicAdd(&cnt[(int)(v & 127)], 1);
    atomicAdd(&wsum[(int)(v & 127)], __uint_as_float((unsigned)(v >> 32)));
  }
  __syncthreads();
  if (t < 128) sc[t] = cnt[t];
  __syncthreads();
  for (int d = 1; d < 128; d <<= 1) {
    int v = (t < 128 && t >= d) ? sc[t - d] : 0;
    __syncthreads();
    if (t < 128) sc[t] += v;
    __syncthreads();
  }
  int node = b * 128 + t;
  if (t < 128 && node < N_NODES) {
    off[node] = s + sc[t] - cnt[t];
    dinv[node] = rsqrtf(wsum[t]);
  }
  __syncthreads();
  for (int i = s + t; i < e; i += 256) {
    unsigned long long v = bucketed[i];
    int cl = (int)(v & 127);
    int r = (int)((v >> BSH) & 0xFFFF);
    float w = __uint_as_float((unsigned)(v >> 32));
    int rank = atomicAdd(&cnt2[cl], 1);
    int pos = s + sc[cl] - cnt[cl] + rank;
    cpack[pos] = ((unsigned int)f2b(w) << 16) | (unsigned int)r;
  }
  if (b == 0 && t == 0) off[N_NODES] = N_EDGES;
}

// ---------------- MFMA bf16 GEMM, epilogue: fp8(dinv[row] * acc) ----------------
__global__ __launch_bounds__(256) void gemm_mfma_k(const unsigned short* __restrict__ A,
                                                   const unsigned short* __restrict__ W16,
                                                   const float* __restrict__ dinv,
                                                   unsigned char* __restrict__ Out8) {
  __shared__ unsigned short Wl[128 * 128];
  int t = threadIdx.x;
  for (int idx = t; idx < 2048; idx += 256) {
    int n = idx >> 4, G = idx & 15;
    short8v v = *(const short8v*)(W16 + n * 128 + G * 8);
    int Gs = G ^ (n & 15);
    *(short8v*)(&Wl[n * 128 + Gs * 8]) = v;
  }
  __syncthreads();

  int wave = t >> 6, lane = t & 63;
  int l15 = lane & 15, l4 = lane >> 4;
  int rbase = blockIdx.x * 128 + wave * 32;

  float4v acc[2][8];
#pragma unroll
  for (int m = 0; m < 2; ++m)
#pragma unroll
    for (int f = 0; f < 8; ++f) acc[m][f] = (float4v){0.f, 0.f, 0.f, 0.f};

  int r0 = rbase + l15;        if (r0 >= N_NODES) r0 = N_NODES - 1;
  int r1 = rbase + 16 + l15;   if (r1 >= N_NODES) r1 = N_NODES - 1;

#pragma unroll
  for (int s = 0; s < 4; ++s) {
    int kk = s * 32 + l4 * 8;
    short8v a0 = *(const short8v*)(A + (size_t)r0 * 128 + kk);
    short8v a1 = *(const short8v*)(A + (size_t)r1 * 128 + kk);
#pragma unroll
    for (int f = 0; f < 8; ++f) {
      int n = f * 16 + l15;
      int G = s * 4 + l4;
      int Gs = G ^ (n & 15);
      short8v bfr = *(const short8v*)(&Wl[n * 128 + Gs * 8]);
      acc[0][f] = __builtin_amdgcn_mfma_f32_16x16x32_bf16(a0, bfr, acc[0][f], 0, 0, 0);
      acc[1][f] = __builtin_amdgcn_mfma_f32_16x16x32_bf16(a1, bfr, acc[1][f], 0, 0, 0);
    }
  }

#pragma unroll
  for (int m = 0; m < 2; ++m) {
    int rb = rbase + m * 16 + l4 * 4;
#pragma unroll
    for (int r = 0; r < 4; ++r) {
      int row = rb + r;
      if (row < N_NODES) {
        float ds = dinv[row];
        unsigned char* orow = Out8 + (size_t)row * 128 + l15;
#pragma unroll
        for (int f = 0; f < 8; ++f) orow[f * 16] = f2fp8(acc[m][f][r] * ds);
      }
    }
  }
}

// ---------------- aggregate: out[c] = elu(dinv_c*(h8[c] + sum w*h8[r]) + b) ----------------
// h8 rows are fp8 of dinv[r]*(h W^T)[r]; 1 node per wave, 4 waves per block
__global__ __launch_bounds__(256) void aggregate_k(const unsigned char* __restrict__ h8,
                                                   const float* __restrict__ dinv,
                                                   const int* __restrict__ off,
                                                   const unsigned int* __restrict__ cpack,
                                                   const float* __restrict__ bias,
                                                   unsigned short* __restrict__ hout) {
  int c = blockIdx.x * 4 + (threadIdx.x >> 6);
  if (c >= N_NODES) return;
  int t = threadIdx.x & 63;
  int col = t * 2;                      // byte offset within 128B row
  const unsigned short* h8s = (const unsigned short*)h8;
  unsigned int sv = h8s[((size_t)c * 128 + col) >> 1];
  float2v fs = fp8x2_2f(sv);
  float acc0 = fs.x, acc1 = fs.y;
  int s = off[c], e = off[c + 1];
  int k = s;
  for (; k + 8 <= e; k += 8) {
    unsigned int p0 = cpack[k],   p1 = cpack[k+1], p2 = cpack[k+2], p3 = cpack[k+3];
    unsigned int p4 = cpack[k+4], p5 = cpack[k+5], p6 = cpack[k+6], p7 = cpack[k+7];
    unsigned int g0 = h8s[((size_t)(p0 & 0xFFFF) * 128 + col) >> 1];
    unsigned int g1 = h8s[((size_t)(p1 & 0xFFFF) * 128 + col) >> 1];
    unsigned int g2 = h8s[((size_t)(p2 & 0xFFFF) * 128 + col) >> 1];
    unsigned int g3 = h8s[((size_t)(p3 & 0xFFFF) * 128 + col) >> 1];
    unsigned int g4 = h8s[((size_t)(p4 & 0xFFFF) * 128 + col) >> 1];
    unsigned int g5 = h8s[((size_t)(p5 & 0xFFFF) * 128 + col) >> 1];
    unsigned int g6 = h8s[((size_t)(p6 & 0xFFFF) * 128 + col) >> 1];
    unsigned int g7 = h8s[((size_t)(p7 & 0xFFFF) * 128 + col) >> 1];
    float w0 = bhi(p0), w1 = bhi(p1), w2 = bhi(p2), w3 = bhi(p3);
    float w4 = bhi(p4), w5 = bhi(p5), w6 = bhi(p6), w7 = bhi(p7);
    float2v f0 = fp8x2_2f(g0), f1 = fp8x2_2f(g1), f2 = fp8x2_2f(g2), f3 = fp8x2_2f(g3);
    float2v f4 = fp8x2_2f(g4), f5 = fp8x2_2f(g5), f6 = fp8x2_2f(g6), f7 = fp8x2_2f(g7);
    acc0 += w0 * f0.x + w1 * f1.x + w2 * f2.x + w3 * f3.x;
    acc1 += w0 * f0.y + w1 * f1.y + w2 * f2.y + w3 * f3.y;
    acc0 += w4 * f4.x + w5 * f5.x + w6 * f6.x + w7 * f7.x;
    acc1 += w4 * f4.y + w5 * f5.y + w6 * f6.y + w7 * f7.y;
  }
  for (; k < e; ++k) {
    unsigned int p = cpack[k];
    unsigned int g = h8s[((size_t)(p & 0xFFFF) * 128 + col) >> 1];
    float w = bhi(p);
    float2v f = fp8x2_2f(g);
    acc0 += w * f.x; acc1 += w * f.y;
  }
  float dc = dinv[c];
  acc0 = dc * acc0 + bias[col];
  acc1 = dc * acc1 + bias[col + 1];
  acc0 = acc0 > 0.f ? acc0 : expm1f(acc0);
  acc1 = acc1 > 0.f ? acc1 : expm1f(acc1);
  unsigned int o = (unsigned int)f2b(acc0) | ((unsigned int)f2b(acc1) << 16);
  *(unsigned int*)(hout + (size_t)c * 128 + col) = o;
}

// ---------------- fused mean-pool + head ----------------
__global__ __launch_bounds__(128) void poolhead_k(const unsigned short* __restrict__ h,
                                                  const int* __restrict__ batch,
                                                  const float* __restrict__ fc1w, const float* __restrict__ fc1b,
                                                  const float* __restrict__ fc2w, const float* __restrict__ fc2b,
                                                  float* __restrict__ out) {
  __shared__ float ps[HDIM];
  __shared__ float z1[HDIM];
  __shared__ float z2[NCLS];
  int g = blockIdx.x, t = threadIdx.x;
  int lo = 0, hi = N_NODES;
  while (lo < hi) { int mid = (lo + hi) >> 1; if (batch[mid] < g) lo = mid + 1; else hi = mid; }
  int gs = lo;
  hi = N_NODES;
  while (lo < hi) { int mid = (lo + hi) >> 1; if (batch[mid] < g + 1) lo = mid + 1; else hi = mid; }
  int ge = lo;
  float a = 0.f;
  for (int n = gs; n < ge; ++n) a += b2f(h[(size_t)n * 128 + t]);
  ps[t] = a / (float)max(ge - gs, 1);
  __syncthreads();
  float acc = fc1b[t];
  for (int i = 0; i < HDIM; ++i) acc += ps[i] * fc1w[t * HDIM + i];
  z1[t] = (acc > 0.f) ? acc : expm1f(acc);
  __syncthreads();
  if (t < NCLS) {
    float a2 = fc2b[t];
    for (int i = 0; i < HDIM; ++i) a2 += z1[i] * fc2w[t * HDIM + i];
    z2[t] = a2;
  }
  __syncthreads();
  if (t == 0) {
    float m = -1e30f;
    for (int i = 0; i < NCLS; ++i) m = fmaxf(m, z2[i]);
    float s2 = 0.f;
    for (int i = 0; i < NCLS; ++i) s2 += expf(z2[i] - m);
    float l = logf(s2);
    for (int i = 0; i < NCLS; ++i) out[g * NCLS + i] = z2[i] - m - l;
  }
}

// ---------------- launch ----------------
static inline size_t align256(size_t x) { return (x + 255) & ~(size_t)255; }

extern "C" void kernel_launch(void* const* d_in, const int* in_sizes, int n_in,
                              void* d_out, int out_size, void* d_ws, size_t ws_size,
                              hipStream_t stream) {
  const float* x     = (const float*)d_in[0];
  const int*   ei    = (const int*)d_in[1];
  const float* ew    = (const float*)d_in[2];
  const int*   batch = (const int*)d_in[3];
  const float* Wl[4] = { (const float*)d_in[4], (const float*)d_in[6], (const float*)d_in[8], (const float*)d_in[10] };
  const float* bl[4] = { (const float*)d_in[5], (const float*)d_in[7], (const float*)d_in[9], (const float*)d_in[11] };
  const float* fc1w = (const float*)d_in[12];
  const float* fc1b = (const float*)d_in[13];
  const float* fc2w = (const float*)d_in[14];
  const float* fc2b = (const float*)d_in[15];
  float* out = (float*)d_out;

  char* ws = (char*)d_ws;
  size_t o = 0;
  unsigned short* x16 = (unsigned short*)(ws + o); o = align256(o + (size_t)N_NODES * HDIM * 2);
  unsigned short* h16 = (unsigned short*)(ws + o); o = align256(o + (size_t)N_NODES * HDIM * 2);
  // h8 (6.4MB) aliases bucketed (12.8MB): bucketed dead after csrB_k; h8 first
  // written by gemm_mfma_k (launched after csrB_k).
  unsigned char* h8 = (unsigned char*)(ws + o);
  unsigned long long* bucketed = (unsigned long long*)(ws + o);
  o = align256(o + (size_t)N_EDGES * 8);
  unsigned short* w16[4];
  for (int l = 0; l < 4; ++l) { w16[l] = (unsigned short*)(ws + o); o = align256(o + (size_t)HDIM * HDIM * 2); }
  unsigned int* cpack = (unsigned int*)(ws + o); o = align256(o + (size_t)N_EDGES * 4);
  int*   partialB = (int*)(ws + o);   o = align256(o + (size_t)NSLICE * NBUCK * 4);
  int*   boff     = (int*)(ws + o);   o = align256(o + (size_t)(NBUCK + 1) * 4);
  float* dinv  = (float*)(ws + o); o = align256(o + (size_t)N_NODES * 4);
  int*   off   = (int*)  (ws + o); o = align256(o + (size_t)(N_NODES + 1) * 4);

  cast4_k<<<(N_NODES * HDIM / 4 + 255) / 256, 256, 0, stream>>>(x, x16, N_NODES * HDIM / 4);
  castw_k<<<64, 256, 0, stream>>>(Wl[0], Wl[1], Wl[2], Wl[3], w16[0], w16[1], w16[2], w16[3]);

  countA_k<<<NSLICE, 256, 0, stream>>>(ei, partialB);
  prefixA1_k<<<(NBUCK + 255) / 256, 256, 0, stream>>>(partialB, boff);
  prefixA2_k<<<1, 512, 0, stream>>>(boff);
  bucketA_k<<<NSLICE, 256, 0, stream>>>(ei, ew, partialB, boff, bucketed);
  csrB_k<<<NBUCK, 256, 0, stream>>>(bucketed, boff, off, dinv, cpack);

  const unsigned short* hin = x16;
  for (int l = 0; l < 4; ++l) {
    gemm_mfma_k<<<(N_NODES + 127) / 128, 256, 0, stream>>>(hin, w16[l], dinv, h8);
    aggregate_k<<<(N_NODES + 3) / 4, 256, 0, stream>>>(h8, dinv, off, cpack, bl[l], h16);
    hin = h16;
  }

  poolhead_k<<<NGRAPH, 128, 0, stream>>>(h16, batch, fc1w, fc1b, fc2w, fc2b, out);
}

// Round 10
// 297.345 us; speedup vs baseline: 4.0081x; 1.1709x over previous
//
#include <hip/hip_runtime.h>
#include <math.h>

#define N_NODES 50000
#define N_EDGES 1600000
#define HDIM 128
#define NGRAPH 512
#define NCLS 10

#define NSLICE 256
#define EDGES_PER_SLICE (N_EDGES / NSLICE)   // 6250
#define BSH 7                                 // bucket = node >> 7 (128 nodes/bucket)
#define NBUCK 391                             // ceil(N_NODES / 128)

typedef __attribute__((ext_vector_type(8))) short short8v;
typedef __attribute__((ext_vector_type(4))) float float4v;
typedef __attribute__((ext_vector_type(2))) float float2v;

// bf16 helpers
__device__ inline float blo(unsigned int v) { return __uint_as_float(v << 16); }
__device__ inline float bhi(unsigned int v) { return __uint_as_float(v & 0xffff0000u); }
__device__ inline float b2f(unsigned short u) { return __uint_as_float(((unsigned)u) << 16); }
__device__ inline unsigned short f2b(float f) {
  unsigned int u = __float_as_uint(f);
  unsigned int r = u + 0x7fffu + ((u >> 16) & 1u);   // RNE
  return (unsigned short)(r >> 16);
}
// fp8 e4m3 (OCP) hardware converts
__device__ inline unsigned char f2fp8(float f) {
  return (unsigned char)(__builtin_amdgcn_cvt_pk_fp8_f32(f, 0.f, 0, false) & 0xFF);
}
__device__ inline float2v fp8x2lo(unsigned int u) {
  return __builtin_amdgcn_cvt_pk_f32_fp8(u, false);   // bytes 0,1
}
__device__ inline float2v fp8x2hi(unsigned int u) {
  return __builtin_amdgcn_cvt_pk_f32_fp8(u, true);    // bytes 2,3
}

// ---------------- fp32 -> bf16 cast ----------------
__global__ __launch_bounds__(256) void cast4_k(const float* __restrict__ in, unsigned short* __restrict__ out, int n4) {
  int i = blockIdx.x * 256 + threadIdx.x;
  if (i < n4) {
    float4 v = ((const float4*)in)[i];
    ushort4 o;
    o.x = f2b(v.x); o.y = f2b(v.y); o.z = f2b(v.z); o.w = f2b(v.w);
    ((ushort4*)out)[i] = o;
  }
}

// all 4 layer weights in one launch (4 x 16384 fp32, 4 elems/thread)
__global__ __launch_bounds__(256) void castw_k(const float* __restrict__ w0, const float* __restrict__ w1,
                                               const float* __restrict__ w2, const float* __restrict__ w3,
                                               unsigned short* __restrict__ o0, unsigned short* __restrict__ o1,
                                               unsigned short* __restrict__ o2, unsigned short* __restrict__ o3) {
  int i = blockIdx.x * 256 + threadIdx.x;         // 0 .. 16383
  int l = i >> 12, j = i & 4095;                  // 4096 float4 per weight
  const float* in = (l == 0) ? w0 : (l == 1) ? w1 : (l == 2) ? w2 : w3;
  unsigned short* out = (l == 0) ? o0 : (l == 1) ? o1 : (l == 2) ? o2 : o3;
  float4 v = ((const float4*)in)[j];
  ushort4 o;
  o.x = f2b(v.x); o.y = f2b(v.y); o.z = f2b(v.z); o.w = f2b(v.w);
  ((ushort4*)out)[j] = o;
}

// ---------------- phase A1: per-slice coarse-bucket histogram ----------------
__global__ __launch_bounds__(256) void countA_k(const int* __restrict__ ei, int* __restrict__ partialB) {
  __shared__ int cnt[NBUCK];
  int s = blockIdx.x, t = threadIdx.x;
  for (int i = t; i < NBUCK; i += 256) cnt[i] = 0;
  __syncthreads();
  int base = s * EDGES_PER_SLICE;
  for (int i = t; i < EDGES_PER_SLICE; i += 256) {
    int c = ei[N_EDGES + base + i];
    atomicAdd(&cnt[c >> BSH], 1);
  }
  __syncthreads();
  for (int i = t; i < NBUCK; i += 256) partialB[s * NBUCK + i] = cnt[i];
}

// ---------------- phase A2a: per-bucket exclusive prefix over slices ----------------
__global__ __launch_bounds__(256) void prefixA1_k(int* __restrict__ partialB, int* __restrict__ boff) {
  int b = blockIdx.x * 256 + threadIdx.x;
  if (b >= NBUCK) return;
  int acc = 0;
  for (int s = 0; s < NSLICE; ++s) {
    int v = partialB[s * NBUCK + b];
    partialB[s * NBUCK + b] = acc;
    acc += v;
  }
  boff[b] = acc;
}

// ---------------- phase A2b: exclusive scan of bucket totals (1 block) ----------------
__global__ __launch_bounds__(512) void prefixA2_k(int* __restrict__ boff) {
  __shared__ int sd[512];
  int t = threadIdx.x;
  int my = (t < NBUCK) ? boff[t] : 0;
  sd[t] = my;
  __syncthreads();
  for (int d = 1; d < 512; d <<= 1) {
    int v = (t >= d) ? sd[t - d] : 0;
    __syncthreads();
    sd[t] += v;
    __syncthreads();
  }
  if (t < NBUCK) boff[t] = sd[t] - my;
  if (t == 511) boff[NBUCK] = sd[511];
}

// ---------------- phase A3: scatter edges into coarse buckets (packed 8B) ----------------
// record: w(32) << 32 | r(16) << 7 | c_local(7)
__global__ __launch_bounds__(256) void bucketA_k(const int* __restrict__ ei, const float* __restrict__ ew,
                                                 const int* __restrict__ partialB, const int* __restrict__ boff,
                                                 unsigned long long* __restrict__ bucketed) {
  __shared__ int rnk[NBUCK];
  __shared__ int sbase[NBUCK];
  int s = blockIdx.x, t = threadIdx.x;
  for (int i = t; i < NBUCK; i += 256) { rnk[i] = 0; sbase[i] = boff[i] + partialB[s * NBUCK + i]; }
  __syncthreads();
  int base = s * EDGES_PER_SLICE;
  for (int i = t; i < EDGES_PER_SLICE; i += 256) {
    int c = ei[N_EDGES + base + i];
    int r = ei[base + i];
    float w = ew[base + i];
    int bk = c >> BSH;
    int rank = atomicAdd(&rnk[bk], 1);
    unsigned long long v = ((unsigned long long)__float_as_uint(w) << 32)
                         | ((unsigned long long)(unsigned)r << BSH)
                         | (unsigned long long)(c & 127);
    bucketed[(size_t)sbase[bk] + rank] = v;
  }
}

// ---------------- phase B: per-bucket degree + CSR build (fused, block-exclusive) ----------------
// cpack = bf16(w)<<16 | r   (dinv folded into rows / applied at aggregate)
__global__ __launch_bounds__(256) void csrB_k(const unsigned long long* __restrict__ bucketed,
                                              const int* __restrict__ boff,
                                              int* __restrict__ off, float* __restrict__ dinv,
                                              unsigned int* __restrict__ cpack) {
  __shared__ int cnt[128];
  __shared__ float wsum[128];
  __shared__ int sc[128];
  __shared__ int cnt2[128];
  int b = blockIdx.x, t = threadIdx.x;
  if (t < 128) { cnt[t] = 0; cnt2[t] = 0; wsum[t] = 1.0f; }   // self-loop weight
  __syncthreads();
  int s = boff[b], e = boff[b + 1];
  for (int i = s + t; i < e; i += 256) {
    unsigned long long v = bucketed[i];
    atomicAdd(&cnt[(int)(v & 127)], 1);
    atomicAdd(&wsum[(int)(v & 127)], __uint_as_float((unsigned)(v >> 32)));
  }
  __syncthreads();
  if (t < 128) sc[t] = cnt[t];
  __syncthreads();
  for (int d = 1; d < 128; d <<= 1) {
    int v = (t < 128 && t >= d) ? sc[t - d] : 0;
    __syncthreads();
    if (t < 128) sc[t] += v;
    __syncthreads();
  }
  int node = b * 128 + t;
  if (t < 128 && node < N_NODES) {
    off[node] = s + sc[t] - cnt[t];
    dinv[node] = rsqrtf(wsum[t]);
  }
  __syncthreads();
  for (int i = s + t; i < e; i += 256) {
    unsigned long long v = bucketed[i];
    int cl = (int)(v & 127);
    int r = (int)((v >> BSH) & 0xFFFF);
    float w = __uint_as_float((unsigned)(v >> 32));
    int rank = atomicAdd(&cnt2[cl], 1);
    int pos = s + sc[cl] - cnt[cl] + rank;
    cpack[pos] = ((unsigned int)f2b(w) << 16) | (unsigned int)r;
  }
  if (b == 0 && t == 0) off[N_NODES] = N_EDGES;
}

// ---------------- MFMA bf16 GEMM, epilogue: fp8(dinv[row] * acc) ----------------
__global__ __launch_bounds__(256) void gemm_mfma_k(const unsigned short* __restrict__ A,
                                                   const unsigned short* __restrict__ W16,
                                                   const float* __restrict__ dinv,
                                                   unsigned char* __restrict__ Out8) {
  __shared__ unsigned short Wl[128 * 128];
  int t = threadIdx.x;
  for (int idx = t; idx < 2048; idx += 256) {
    int n = idx >> 4, G = idx & 15;
    short8v v = *(const short8v*)(W16 + n * 128 + G * 8);
    int Gs = G ^ (n & 15);
    *(short8v*)(&Wl[n * 128 + Gs * 8]) = v;
  }
  __syncthreads();

  int wave = t >> 6, lane = t & 63;
  int l15 = lane & 15, l4 = lane >> 4;
  int rbase = blockIdx.x * 128 + wave * 32;

  float4v acc[2][8];
#pragma unroll
  for (int m = 0; m < 2; ++m)
#pragma unroll
    for (int f = 0; f < 8; ++f) acc[m][f] = (float4v){0.f, 0.f, 0.f, 0.f};

  int r0 = rbase + l15;        if (r0 >= N_NODES) r0 = N_NODES - 1;
  int r1 = rbase + 16 + l15;   if (r1 >= N_NODES) r1 = N_NODES - 1;

#pragma unroll
  for (int s = 0; s < 4; ++s) {
    int kk = s * 32 + l4 * 8;
    short8v a0 = *(const short8v*)(A + (size_t)r0 * 128 + kk);
    short8v a1 = *(const short8v*)(A + (size_t)r1 * 128 + kk);
#pragma unroll
    for (int f = 0; f < 8; ++f) {
      int n = f * 16 + l15;
      int G = s * 4 + l4;
      int Gs = G ^ (n & 15);
      short8v bfr = *(const short8v*)(&Wl[n * 128 + Gs * 8]);
      acc[0][f] = __builtin_amdgcn_mfma_f32_16x16x32_bf16(a0, bfr, acc[0][f], 0, 0, 0);
      acc[1][f] = __builtin_amdgcn_mfma_f32_16x16x32_bf16(a1, bfr, acc[1][f], 0, 0, 0);
    }
  }

#pragma unroll
  for (int m = 0; m < 2; ++m) {
    int rb = rbase + m * 16 + l4 * 4;
#pragma unroll
    for (int r = 0; r < 4; ++r) {
      int row = rb + r;
      if (row < N_NODES) {
        float ds = dinv[row];
        unsigned char* orow = Out8 + (size_t)row * 128 + l15;
#pragma unroll
        for (int f = 0; f < 8; ++f) orow[f * 16] = f2fp8(acc[m][f][r] * ds);
      }
    }
  }
}

// ---------------- aggregate: out[c] = elu(dinv_c*(h8[c] + sum w*h8[r]) + b) ----------------
// 32 lanes per node (4 fp8 features per lane), 2 nodes per wave, 8 nodes per block
__global__ __launch_bounds__(256) void aggregate_k(const unsigned char* __restrict__ h8,
                                                   const float* __restrict__ dinv,
                                                   const int* __restrict__ off,
                                                   const unsigned int* __restrict__ cpack,
                                                   const float* __restrict__ bias,
                                                   unsigned short* __restrict__ hout) {
  int c = blockIdx.x * 8 + (threadIdx.x >> 5);
  if (c >= N_NODES) return;
  int fl = threadIdx.x & 31;            // feature lane: features 4fl..4fl+3
  const unsigned int* h8w = (const unsigned int*)h8;   // 32 u32 per row
  unsigned int sv = h8w[((size_t)c << 5) + fl];
  float2v slo = fp8x2lo(sv), shi = fp8x2hi(sv);
  float acc0 = slo.x, acc1 = slo.y, acc2 = shi.x, acc3 = shi.y;
  int s = off[c], e = off[c + 1];
  int k = s;
  for (; k + 8 <= e; k += 8) {
    unsigned int p0 = cpack[k],   p1 = cpack[k+1], p2 = cpack[k+2], p3 = cpack[k+3];
    unsigned int p4 = cpack[k+4], p5 = cpack[k+5], p6 = cpack[k+6], p7 = cpack[k+7];
    unsigned int g0 = h8w[((size_t)(p0 & 0xFFFF) << 5) + fl];
    unsigned int g1 = h8w[((size_t)(p1 & 0xFFFF) << 5) + fl];
    unsigned int g2 = h8w[((size_t)(p2 & 0xFFFF) << 5) + fl];
    unsigned int g3 = h8w[((size_t)(p3 & 0xFFFF) << 5) + fl];
    unsigned int g4 = h8w[((size_t)(p4 & 0xFFFF) << 5) + fl];
    unsigned int g5 = h8w[((size_t)(p5 & 0xFFFF) << 5) + fl];
    unsigned int g6 = h8w[((size_t)(p6 & 0xFFFF) << 5) + fl];
    unsigned int g7 = h8w[((size_t)(p7 & 0xFFFF) << 5) + fl];
    float w0 = bhi(p0), w1 = bhi(p1), w2 = bhi(p2), w3 = bhi(p3);
    float w4 = bhi(p4), w5 = bhi(p5), w6 = bhi(p6), w7 = bhi(p7);
    float2v l0 = fp8x2lo(g0), h0 = fp8x2hi(g0);
    float2v l1 = fp8x2lo(g1), h1 = fp8x2hi(g1);
    float2v l2 = fp8x2lo(g2), h2 = fp8x2hi(g2);
    float2v l3 = fp8x2lo(g3), h3 = fp8x2hi(g3);
    float2v l4 = fp8x2lo(g4), h4 = fp8x2hi(g4);
    float2v l5 = fp8x2lo(g5), h5 = fp8x2hi(g5);
    float2v l6 = fp8x2lo(g6), h6 = fp8x2hi(g6);
    float2v l7 = fp8x2lo(g7), h7 = fp8x2hi(g7);
    acc0 += w0*l0.x + w1*l1.x + w2*l2.x + w3*l3.x;
    acc1 += w0*l0.y + w1*l1.y + w2*l2.y + w3*l3.y;
    acc2 += w0*h0.x + w1*h1.x + w2*h2.x + w3*h3.x;
    acc3 += w0*h0.y + w1*h1.y + w2*h2.y + w3*h3.y;
    acc0 += w4*l4.x + w5*l5.x + w6*l6.x + w7*l7.x;
    acc1 += w4*l4.y + w5*l5.y + w6*l6.y + w7*l7.y;
    acc2 += w4*h4.x + w5*h5.x + w6*h6.x + w7*h7.x;
    acc3 += w4*h4.y + w5*h5.y + w6*h6.y + w7*h7.y;
  }
  for (; k < e; ++k) {
    unsigned int p = cpack[k];
    unsigned int g = h8w[((size_t)(p & 0xFFFF) << 5) + fl];
    float w = bhi(p);
    float2v lo = fp8x2lo(g), hi = fp8x2hi(g);
    acc0 += w * lo.x; acc1 += w * lo.y; acc2 += w * hi.x; acc3 += w * hi.y;
  }
  float dc = dinv[c];
  int col = fl * 4;
  float4 bv = *(const float4*)(bias + col);
  acc0 = dc * acc0 + bv.x;
  acc1 = dc * acc1 + bv.y;
  acc2 = dc * acc2 + bv.z;
  acc3 = dc * acc3 + bv.w;
  acc0 = acc0 > 0.f ? acc0 : expm1f(acc0);
  acc1 = acc1 > 0.f ? acc1 : expm1f(acc1);
  acc2 = acc2 > 0.f ? acc2 : expm1f(acc2);
  acc3 = acc3 > 0.f ? acc3 : expm1f(acc3);
  ushort4 o;
  o.x = f2b(acc0); o.y = f2b(acc1); o.z = f2b(acc2); o.w = f2b(acc3);
  *(ushort4*)(hout + (size_t)c * 128 + col) = o;
}

// ---------------- fused mean-pool + head ----------------
__global__ __launch_bounds__(128) void poolhead_k(const unsigned short* __restrict__ h,
                                                  const int* __restrict__ batch,
                                                  const float* __restrict__ fc1w, const float* __restrict__ fc1b,
                                                  const float* __restrict__ fc2w, const float* __restrict__ fc2b,
                                                  float* __restrict__ out) {
  __shared__ float ps[HDIM];
  __shared__ float z1[HDIM];
  __shared__ float z2[NCLS];
  int g = blockIdx.x, t = threadIdx.x;
  int lo = 0, hi = N_NODES;
  while (lo < hi) { int mid = (lo + hi) >> 1; if (batch[mid] < g) lo = mid + 1; else hi = mid; }
  int gs = lo;
  hi = N_NODES;
  while (lo < hi) { int mid = (lo + hi) >> 1; if (batch[mid] < g + 1) lo = mid + 1; else hi = mid; }
  int ge = lo;
  float a = 0.f;
  for (int n = gs; n < ge; ++n) a += b2f(h[(size_t)n * 128 + t]);
  ps[t] = a / (float)max(ge - gs, 1);
  __syncthreads();
  float acc = fc1b[t];
  for (int i = 0; i < HDIM; ++i) acc += ps[i] * fc1w[t * HDIM + i];
  z1[t] = (acc > 0.f) ? acc : expm1f(acc);
  __syncthreads();
  if (t < NCLS) {
    float a2 = fc2b[t];
    for (int i = 0; i < HDIM; ++i) a2 += z1[i] * fc2w[t * HDIM + i];
    z2[t] = a2;
  }
  __syncthreads();
  if (t == 0) {
    float m = -1e30f;
    for (int i = 0; i < NCLS; ++i) m = fmaxf(m, z2[i]);
    float s2 = 0.f;
    for (int i = 0; i < NCLS; ++i) s2 += expf(z2[i] - m);
    float l = logf(s2);
    for (int i = 0; i < NCLS; ++i) out[g * NCLS + i] = z2[i] - m - l;
  }
}

// ---------------- launch ----------------
static inline size_t align256(size_t x) { return (x + 255) & ~(size_t)255; }

extern "C" void kernel_launch(void* const* d_in, const int* in_sizes, int n_in,
                              void* d_out, int out_size, void* d_ws, size_t ws_size,
                              hipStream_t stream) {
  const float* x     = (const float*)d_in[0];
  const int*   ei    = (const int*)d_in[1];
  const float* ew    = (const float*)d_in[2];
  const int*   batch = (const int*)d_in[3];
  const float* Wl[4] = { (const float*)d_in[4], (const float*)d_in[6], (const float*)d_in[8], (const float*)d_in[10] };
  const float* bl[4] = { (const float*)d_in[5], (const float*)d_in[7], (const float*)d_in[9], (const float*)d_in[11] };
  const float* fc1w = (const float*)d_in[12];
  const float* fc1b = (const float*)d_in[13];
  const float* fc2w = (const float*)d_in[14];
  const float* fc2b = (const float*)d_in[15];
  float* out = (float*)d_out;

  char* ws = (char*)d_ws;
  size_t o = 0;
  unsigned short* x16 = (unsigned short*)(ws + o); o = align256(o + (size_t)N_NODES * HDIM * 2);
  unsigned short* h16 = (unsigned short*)(ws + o); o = align256(o + (size_t)N_NODES * HDIM * 2);
  // h8 (6.4MB) aliases bucketed (12.8MB): bucketed dead after csrB_k; h8 first
  // written by gemm_mfma_k (launched after csrB_k).
  unsigned char* h8 = (unsigned char*)(ws + o);
  unsigned long long* bucketed = (unsigned long long*)(ws + o);
  o = align256(o + (size_t)N_EDGES * 8);
  unsigned short* w16[4];
  for (int l = 0; l < 4; ++l) { w16[l] = (unsigned short*)(ws + o); o = align256(o + (size_t)HDIM * HDIM * 2); }
  unsigned int* cpack = (unsigned int*)(ws + o); o = align256(o + (size_t)N_EDGES * 4);
  int*   partialB = (int*)(ws + o);   o = align256(o + (size_t)NSLICE * NBUCK * 4);
  int*   boff     = (int*)(ws + o);   o = align256(o + (size_t)(NBUCK + 1) * 4);
  float* dinv  = (float*)(ws + o); o = align256(o + (size_t)N_NODES * 4);
  int*   off   = (int*)  (ws + o); o = align256(o + (size_t)(N_NODES + 1) * 4);

  cast4_k<<<(N_NODES * HDIM / 4 + 255) / 256, 256, 0, stream>>>(x, x16, N_NODES * HDIM / 4);
  castw_k<<<64, 256, 0, stream>>>(Wl[0], Wl[1], Wl[2], Wl[3], w16[0], w16[1], w16[2], w16[3]);

  countA_k<<<NSLICE, 256, 0, stream>>>(ei, partialB);
  prefixA1_k<<<(NBUCK + 255) / 256, 256, 0, stream>>>(partialB, boff);
  prefixA2_k<<<1, 512, 0, stream>>>(boff);
  bucketA_k<<<NSLICE, 256, 0, stream>>>(ei, ew, partialB, boff, bucketed);
  csrB_k<<<NBUCK, 256, 0, stream>>>(bucketed, boff, off, dinv, cpack);

  const unsigned short* hin = x16;
  for (int l = 0; l < 4; ++l) {
    gemm_mfma_k<<<(N_NODES + 127) / 128, 256, 0, stream>>>(hin, w16[l], dinv, h8);
    aggregate_k<<<(N_NODES + 7) / 8, 256, 0, stream>>>(h8, dinv, off, cpack, bl[l], h16);
    hin = h16;
  }

  poolhead_k<<<NGRAPH, 128, 0, stream>>>(h16, batch, fc1w, fc1b, fc2w, fc2b, out);
}

// Round 11
// 272.171 us; speedup vs baseline: 4.3788x; 1.0925x over previous
//
#include <hip/hip_runtime.h>
#include <math.h>

#define N_NODES 50000
#define N_EDGES 1600000
#define HDIM 128
#define NGRAPH 512
#define NCLS 10

#define NSLICE 256
#define EDGES_PER_SLICE (N_EDGES / NSLICE)   // 6250
#define BSH 7                                 // bucket = node >> 7 (128 nodes/bucket)
#define NBUCK 391                             // ceil(N_NODES / 128)

typedef __attribute__((ext_vector_type(8))) short short8v;
typedef __attribute__((ext_vector_type(4))) float float4v;
typedef __attribute__((ext_vector_type(2))) float float2v;

// bf16 helpers
__device__ inline float blo(unsigned int v) { return __uint_as_float(v << 16); }
__device__ inline float bhi(unsigned int v) { return __uint_as_float(v & 0xffff0000u); }
__device__ inline float b2f(unsigned short u) { return __uint_as_float(((unsigned)u) << 16); }
__device__ inline unsigned short f2b(float f) {
  unsigned int u = __float_as_uint(f);
  unsigned int r = u + 0x7fffu + ((u >> 16) & 1u);   // RNE
  return (unsigned short)(r >> 16);
}
// fp8 e4m3 (OCP) hardware converts
__device__ inline unsigned char f2fp8(float f) {
  return (unsigned char)(__builtin_amdgcn_cvt_pk_fp8_f32(f, 0.f, 0, false) & 0xFF);
}
__device__ inline float2v fp8x2lo(unsigned int u) {
  return __builtin_amdgcn_cvt_pk_f32_fp8(u, false);   // bytes 0,1
}
__device__ inline float2v fp8x2hi(unsigned int u) {
  return __builtin_amdgcn_cvt_pk_f32_fp8(u, true);    // bytes 2,3
}

// ---------------- fp32 -> bf16 cast ----------------
__global__ __launch_bounds__(256) void cast4_k(const float* __restrict__ in, unsigned short* __restrict__ out, int n4) {
  int i = blockIdx.x * 256 + threadIdx.x;
  if (i < n4) {
    float4 v = ((const float4*)in)[i];
    ushort4 o;
    o.x = f2b(v.x); o.y = f2b(v.y); o.z = f2b(v.z); o.w = f2b(v.w);
    ((ushort4*)out)[i] = o;
  }
}

// all 4 layer weights in one launch (4 x 16384 fp32, 4 elems/thread)
__global__ __launch_bounds__(256) void castw_k(const float* __restrict__ w0, const float* __restrict__ w1,
                                               const float* __restrict__ w2, const float* __restrict__ w3,
                                               unsigned short* __restrict__ o0, unsigned short* __restrict__ o1,
                                               unsigned short* __restrict__ o2, unsigned short* __restrict__ o3) {
  int i = blockIdx.x * 256 + threadIdx.x;         // 0 .. 16383
  int l = i >> 12, j = i & 4095;                  // 4096 float4 per weight
  const float* in = (l == 0) ? w0 : (l == 1) ? w1 : (l == 2) ? w2 : w3;
  unsigned short* out = (l == 0) ? o0 : (l == 1) ? o1 : (l == 2) ? o2 : o3;
  float4 v = ((const float4*)in)[j];
  ushort4 o;
  o.x = f2b(v.x); o.y = f2b(v.y); o.z = f2b(v.z); o.w = f2b(v.w);
  ((ushort4*)out)[j] = o;
}

// ---------------- phase A1: per-slice coarse-bucket histogram ----------------
__global__ __launch_bounds__(256) void countA_k(const int* __restrict__ ei, int* __restrict__ partialB) {
  __shared__ int cnt[NBUCK];
  int s = blockIdx.x, t = threadIdx.x;
  for (int i = t; i < NBUCK; i += 256) cnt[i] = 0;
  __syncthreads();
  int base = s * EDGES_PER_SLICE;
  for (int i = t; i < EDGES_PER_SLICE; i += 256) {
    int c = ei[N_EDGES + base + i];
    atomicAdd(&cnt[c >> BSH], 1);
  }
  __syncthreads();
  for (int i = t; i < NBUCK; i += 256) partialB[s * NBUCK + i] = cnt[i];
}

// ---------------- phase A2a: per-bucket exclusive prefix over slices ----------------
__global__ __launch_bounds__(256) void prefixA1_k(int* __restrict__ partialB, int* __restrict__ boff) {
  int b = blockIdx.x * 256 + threadIdx.x;
  if (b >= NBUCK) return;
  int acc = 0;
  for (int s = 0; s < NSLICE; ++s) {
    int v = partialB[s * NBUCK + b];
    partialB[s * NBUCK + b] = acc;
    acc += v;
  }
  boff[b] = acc;
}

// ---------------- phase A2b: exclusive scan of bucket totals (1 block) ----------------
__global__ __launch_bounds__(512) void prefixA2_k(int* __restrict__ boff) {
  __shared__ int sd[512];
  int t = threadIdx.x;
  int my = (t < NBUCK) ? boff[t] : 0;
  sd[t] = my;
  __syncthreads();
  for (int d = 1; d < 512; d <<= 1) {
    int v = (t >= d) ? sd[t - d] : 0;
    __syncthreads();
    sd[t] += v;
    __syncthreads();
  }
  if (t < NBUCK) boff[t] = sd[t] - my;
  if (t == 511) boff[NBUCK] = sd[511];
}

// ---------------- phase A3: scatter edges into coarse buckets (packed 8B) ----------------
// record: w(32) << 32 | r(16) << 7 | c_local(7)
__global__ __launch_bounds__(256) void bucketA_k(const int* __restrict__ ei, const float* __restrict__ ew,
                                                 const int* __restrict__ partialB, const int* __restrict__ boff,
                                                 unsigned long long* __restrict__ bucketed) {
  __shared__ int rnk[NBUCK];
  __shared__ int sbase[NBUCK];
  int s = blockIdx.x, t = threadIdx.x;
  for (int i = t; i < NBUCK; i += 256) { rnk[i] = 0; sbase[i] = boff[i] + partialB[s * NBUCK + i]; }
  __syncthreads();
  int base = s * EDGES_PER_SLICE;
  for (int i = t; i < EDGES_PER_SLICE; i += 256) {
    int c = ei[N_EDGES + base + i];
    int r = ei[base + i];
    float w = ew[base + i];
    int bk = c >> BSH;
    int rank = atomicAdd(&rnk[bk], 1);
    unsigned long long v = ((unsigned long long)__float_as_uint(w) << 32)
                         | ((unsigned long long)(unsigned)r << BSH)
                         | (unsigned long long)(c & 127);
    bucketed[(size_t)sbase[bk] + rank] = v;
  }
}

// ---------------- phase B: per-bucket degree + CSR build (fused, block-exclusive) ----------------
// cpack = bf16(w)<<16 | r   (dinv folded into rows / applied at aggregate)
__global__ __launch_bounds__(256) void csrB_k(const unsigned long long* __restrict__ bucketed,
                                              const int* __restrict__ boff,
                                              int* __restrict__ off, float* __restrict__ dinv,
                                              unsigned int* __restrict__ cpack) {
  __shared__ int cnt[128];
  __shared__ float wsum[128];
  __shared__ int sc[128];
  __shared__ int cnt2[128];
  int b = blockIdx.x, t = threadIdx.x;
  if (t < 128) { cnt[t] = 0; cnt2[t] = 0; wsum[t] = 1.0f; }   // self-loop weight
  __syncthreads();
  int s = boff[b], e = boff[b + 1];
  for (int i = s + t; i < e; i += 256) {
    unsigned long long v = bucketed[i];
    atomicAdd(&cnt[(int)(v & 127)], 1);
    atomicAdd(&wsum[(int)(v & 127)], __uint_as_float((unsigned)(v >> 32)));
  }
  __syncthreads();
  if (t < 128) sc[t] = cnt[t];
  __syncthreads();
  for (int d = 1; d < 128; d <<= 1) {
    int v = (t < 128 && t >= d) ? sc[t - d] : 0;
    __syncthreads();
    if (t < 128) sc[t] += v;
    __syncthreads();
  }
  int node = b * 128 + t;
  if (t < 128 && node < N_NODES) {
    off[node] = s + sc[t] - cnt[t];
    dinv[node] = rsqrtf(wsum[t]);
  }
  __syncthreads();
  for (int i = s + t; i < e; i += 256) {
    unsigned long long v = bucketed[i];
    int cl = (int)(v & 127);
    int r = (int)((v >> BSH) & 0xFFFF);
    float w = __uint_as_float((unsigned)(v >> 32));
    int rank = atomicAdd(&cnt2[cl], 1);
    int pos = s + sc[cl] - cnt[cl] + rank;
    cpack[pos] = ((unsigned int)f2b(w) << 16) | (unsigned int)r;
  }
  if (b == 0 && t == 0) off[N_NODES] = N_EDGES;
}

// ---------------- MFMA bf16 GEMM, epilogue: fp8(dinv[row] * acc) ----------------
__global__ __launch_bounds__(256) void gemm_mfma_k(const unsigned short* __restrict__ A,
                                                   const unsigned short* __restrict__ W16,
                                                   const float* __restrict__ dinv,
                                                   unsigned char* __restrict__ Out8) {
  __shared__ unsigned short Wl[128 * 128];
  int t = threadIdx.x;
  for (int idx = t; idx < 2048; idx += 256) {
    int n = idx >> 4, G = idx & 15;
    short8v v = *(const short8v*)(W16 + n * 128 + G * 8);
    int Gs = G ^ (n & 15);
    *(short8v*)(&Wl[n * 128 + Gs * 8]) = v;
  }
  __syncthreads();

  int wave = t >> 6, lane = t & 63;
  int l15 = lane & 15, l4 = lane >> 4;
  int rbase = blockIdx.x * 128 + wave * 32;

  float4v acc[2][8];
#pragma unroll
  for (int m = 0; m < 2; ++m)
#pragma unroll
    for (int f = 0; f < 8; ++f) acc[m][f] = (float4v){0.f, 0.f, 0.f, 0.f};

  int r0 = rbase + l15;        if (r0 >= N_NODES) r0 = N_NODES - 1;
  int r1 = rbase + 16 + l15;   if (r1 >= N_NODES) r1 = N_NODES - 1;

#pragma unroll
  for (int s = 0; s < 4; ++s) {
    int kk = s * 32 + l4 * 8;
    short8v a0 = *(const short8v*)(A + (size_t)r0 * 128 + kk);
    short8v a1 = *(const short8v*)(A + (size_t)r1 * 128 + kk);
#pragma unroll
    for (int f = 0; f < 8; ++f) {
      int n = f * 16 + l15;
      int G = s * 4 + l4;
      int Gs = G ^ (n & 15);
      short8v bfr = *(const short8v*)(&Wl[n * 128 + Gs * 8]);
      acc[0][f] = __builtin_amdgcn_mfma_f32_16x16x32_bf16(a0, bfr, acc[0][f], 0, 0, 0);
      acc[1][f] = __builtin_amdgcn_mfma_f32_16x16x32_bf16(a1, bfr, acc[1][f], 0, 0, 0);
    }
  }

#pragma unroll
  for (int m = 0; m < 2; ++m) {
    int rb = rbase + m * 16 + l4 * 4;
#pragma unroll
    for (int r = 0; r < 4; ++r) {
      int row = rb + r;
      if (row < N_NODES) {
        float ds = dinv[row];
        unsigned char* orow = Out8 + (size_t)row * 128 + l15;
#pragma unroll
        for (int f = 0; f < 8; ++f) orow[f * 16] = f2fp8(acc[m][f][r] * ds);
      }
    }
  }
}

// ---------------- aggregate: out[c] = elu(dinv_c*(h8[c] + sum w*h8[r]) + b) ----------------
// 32 lanes per node (4 fp8 features per lane), 2 nodes per wave, 8 nodes per block
__global__ __launch_bounds__(256) void aggregate_k(const unsigned char* __restrict__ h8,
                                                   const float* __restrict__ dinv,
                                                   const int* __restrict__ off,
                                                   const unsigned int* __restrict__ cpack,
                                                   const float* __restrict__ bias,
                                                   unsigned short* __restrict__ hout) {
  int c = blockIdx.x * 8 + (threadIdx.x >> 5);
  if (c >= N_NODES) return;
  int fl = threadIdx.x & 31;            // feature lane: features 4fl..4fl+3
  const unsigned int* h8w = (const unsigned int*)h8;   // 32 u32 per row
  unsigned int sv = h8w[((size_t)c << 5) + fl];
  float2v slo = fp8x2lo(sv), shi = fp8x2hi(sv);
  float acc0 = slo.x, acc1 = slo.y, acc2 = shi.x, acc3 = shi.y;
  int s = off[c], e = off[c + 1];
  int k = s;
  for (; k + 8 <= e; k += 8) {
    unsigned int p0 = cpack[k],   p1 = cpack[k+1], p2 = cpack[k+2], p3 = cpack[k+3];
    unsigned int p4 = cpack[k+4], p5 = cpack[k+5], p6 = cpack[k+6], p7 = cpack[k+7];
    unsigned int g0 = h8w[((size_t)(p0 & 0xFFFF) << 5) + fl];
    unsigned int g1 = h8w[((size_t)(p1 & 0xFFFF) << 5) + fl];
    unsigned int g2 = h8w[((size_t)(p2 & 0xFFFF) << 5) + fl];
    unsigned int g3 = h8w[((size_t)(p3 & 0xFFFF) << 5) + fl];
    unsigned int g4 = h8w[((size_t)(p4 & 0xFFFF) << 5) + fl];
    unsigned int g5 = h8w[((size_t)(p5 & 0xFFFF) << 5) + fl];
    unsigned int g6 = h8w[((size_t)(p6 & 0xFFFF) << 5) + fl];
    unsigned int g7 = h8w[((size_t)(p7 & 0xFFFF) << 5) + fl];
    float w0 = bhi(p0), w1 = bhi(p1), w2 = bhi(p2), w3 = bhi(p3);
    float w4 = bhi(p4), w5 = bhi(p5), w6 = bhi(p6), w7 = bhi(p7);
    float2v l0 = fp8x2lo(g0), h0 = fp8x2hi(g0);
    float2v l1 = fp8x2lo(g1), h1 = fp8x2hi(g1);
    float2v l2 = fp8x2lo(g2), h2 = fp8x2hi(g2);
    float2v l3 = fp8x2lo(g3), h3 = fp8x2hi(g3);
    float2v l4 = fp8x2lo(g4), h4 = fp8x2hi(g4);
    float2v l5 = fp8x2lo(g5), h5 = fp8x2hi(g5);
    float2v l6 = fp8x2lo(g6), h6 = fp8x2hi(g6);
    float2v l7 = fp8x2lo(g7), h7 = fp8x2hi(g7);
    acc0 += w0*l0.x + w1*l1.x + w2*l2.x + w3*l3.x;
    acc1 += w0*l0.y + w1*l1.y + w2*l2.y + w3*l3.y;
    acc2 += w0*h0.x + w1*h1.x + w2*h2.x + w3*h3.x;
    acc3 += w0*h0.y + w1*h1.y + w2*h2.y + w3*h3.y;
    acc0 += w4*l4.x + w5*l5.x + w6*l6.x + w7*l7.x;
    acc1 += w4*l4.y + w5*l5.y + w6*l6.y + w7*l7.y;
    acc2 += w4*h4.x + w5*h5.x + w6*h6.x + w7*h7.x;
    acc3 += w4*h4.y + w5*h5.y + w6*h6.y + w7*h7.y;
  }
  for (; k < e; ++k) {
    unsigned int p = cpack[k];
    unsigned int g = h8w[((size_t)(p & 0xFFFF) << 5) + fl];
    float w = bhi(p);
    float2v lo = fp8x2lo(g), hi = fp8x2hi(g);
    acc0 += w * lo.x; acc1 += w * lo.y; acc2 += w * hi.x; acc3 += w * hi.y;
  }
  float dc = dinv[c];
  int col = fl * 4;
  float4 bv = *(const float4*)(bias + col);
  acc0 = dc * acc0 + bv.x;
  acc1 = dc * acc1 + bv.y;
  acc2 = dc * acc2 + bv.z;
  acc3 = dc * acc3 + bv.w;
  acc0 = acc0 > 0.f ? acc0 : expm1f(acc0);
  acc1 = acc1 > 0.f ? acc1 : expm1f(acc1);
  acc2 = acc2 > 0.f ? acc2 : expm1f(acc2);
  acc3 = acc3 > 0.f ? acc3 : expm1f(acc3);
  ushort4 o;
  o.x = f2b(acc0); o.y = f2b(acc1); o.z = f2b(acc2); o.w = f2b(acc3);
  *(ushort4*)(hout + (size_t)c * 128 + col) = o;
}

// ---------------- fused mean-pool + head: 512 thr = 8 node-groups x 64 lanes ----------------
__global__ __launch_bounds__(512) void poolhead_k(const unsigned short* __restrict__ h,
                                                  const int* __restrict__ batch,
                                                  const float* __restrict__ fc1w, const float* __restrict__ fc1b,
                                                  const float* __restrict__ fc2w, const float* __restrict__ fc2b,
                                                  float* __restrict__ out) {
  __shared__ float part[8][HDIM];
  __shared__ float ps[HDIM];
  __shared__ float z1[HDIM];
  __shared__ float z2[NCLS];
  int g = blockIdx.x, t = threadIdx.x;
  int fl = t & 63;            // u32 word: features 2fl, 2fl+1
  int grp = t >> 6;           // 0..7
  int lo = 0, hi = N_NODES;
  while (lo < hi) { int mid = (lo + hi) >> 1; if (batch[mid] < g) lo = mid + 1; else hi = mid; }
  int gs = lo;
  hi = N_NODES;
  while (lo < hi) { int mid = (lo + hi) >> 1; if (batch[mid] < g + 1) lo = mid + 1; else hi = mid; }
  int ge = lo;
  const unsigned int* hw = (const unsigned int*)h;   // 64 u32 per row
  float a0 = 0.f, a1 = 0.f;
  for (int n = gs + grp; n < ge; n += 8) {
    unsigned int v = hw[((size_t)n << 6) + fl];
    a0 += blo(v); a1 += bhi(v);
  }
  part[grp][fl * 2] = a0;
  part[grp][fl * 2 + 1] = a1;
  __syncthreads();
  if (t < HDIM) {
    float s = 0.f;
#pragma unroll
    for (int q = 0; q < 8; ++q) s += part[q][t];
    ps[t] = s / (float)max(ge - gs, 1);
  }
  __syncthreads();
  if (t < HDIM) {
    float acc = fc1b[t];
    for (int i = 0; i < HDIM; ++i) acc += ps[i] * fc1w[t * HDIM + i];
    z1[t] = (acc > 0.f) ? acc : expm1f(acc);
  }
  __syncthreads();
  if (t < NCLS) {
    float a2 = fc2b[t];
    for (int i = 0; i < HDIM; ++i) a2 += z1[i] * fc2w[t * HDIM + i];
    z2[t] = a2;
  }
  __syncthreads();
  if (t == 0) {
    float m = -1e30f;
    for (int i = 0; i < NCLS; ++i) m = fmaxf(m, z2[i]);
    float s2 = 0.f;
    for (int i = 0; i < NCLS; ++i) s2 += expf(z2[i] - m);
    float l = logf(s2);
    for (int i = 0; i < NCLS; ++i) out[g * NCLS + i] = z2[i] - m - l;
  }
}

// ---------------- launch ----------------
static inline size_t align256(size_t x) { return (x + 255) & ~(size_t)255; }

extern "C" void kernel_launch(void* const* d_in, const int* in_sizes, int n_in,
                              void* d_out, int out_size, void* d_ws, size_t ws_size,
                              hipStream_t stream) {
  const float* x     = (const float*)d_in[0];
  const int*   ei    = (const int*)d_in[1];
  const float* ew    = (const float*)d_in[2];
  const int*   batch = (const int*)d_in[3];
  const float* Wl[4] = { (const float*)d_in[4], (const float*)d_in[6], (const float*)d_in[8], (const float*)d_in[10] };
  const float* bl[4] = { (const float*)d_in[5], (const float*)d_in[7], (const float*)d_in[9], (const float*)d_in[11] };
  const float* fc1w = (const float*)d_in[12];
  const float* fc1b = (const float*)d_in[13];
  const float* fc2w = (const float*)d_in[14];
  const float* fc2b = (const float*)d_in[15];
  float* out = (float*)d_out;

  char* ws = (char*)d_ws;
  size_t o = 0;
  unsigned short* x16 = (unsigned short*)(ws + o); o = align256(o + (size_t)N_NODES * HDIM * 2);
  unsigned short* h16 = (unsigned short*)(ws + o); o = align256(o + (size_t)N_NODES * HDIM * 2);
  // h8 (6.4MB) aliases bucketed (12.8MB): bucketed dead after csrB_k; h8 first
  // written by gemm_mfma_k (launched after csrB_k).
  unsigned char* h8 = (unsigned char*)(ws + o);
  unsigned long long* bucketed = (unsigned long long*)(ws + o);
  o = align256(o + (size_t)N_EDGES * 8);
  unsigned short* w16[4];
  for (int l = 0; l < 4; ++l) { w16[l] = (unsigned short*)(ws + o); o = align256(o + (size_t)HDIM * HDIM * 2); }
  unsigned int* cpack = (unsigned int*)(ws + o); o = align256(o + (size_t)N_EDGES * 4);
  int*   partialB = (int*)(ws + o);   o = align256(o + (size_t)NSLICE * NBUCK * 4);
  int*   boff     = (int*)(ws + o);   o = align256(o + (size_t)(NBUCK + 1) * 4);
  float* dinv  = (float*)(ws + o); o = align256(o + (size_t)N_NODES * 4);
  int*   off   = (int*)  (ws + o); o = align256(o + (size_t)(N_NODES + 1) * 4);

  cast4_k<<<(N_NODES * HDIM / 4 + 255) / 256, 256, 0, stream>>>(x, x16, N_NODES * HDIM / 4);
  castw_k<<<64, 256, 0, stream>>>(Wl[0], Wl[1], Wl[2], Wl[3], w16[0], w16[1], w16[2], w16[3]);

  countA_k<<<NSLICE, 256, 0, stream>>>(ei, partialB);
  prefixA1_k<<<(NBUCK + 255) / 256, 256, 0, stream>>>(partialB, boff);
  prefixA2_k<<<1, 512, 0, stream>>>(boff);
  bucketA_k<<<NSLICE, 256, 0, stream>>>(ei, ew, partialB, boff, bucketed);
  csrB_k<<<NBUCK, 256, 0, stream>>>(bucketed, boff, off, dinv, cpack);

  const unsigned short* hin = x16;
  for (int l = 0; l < 4; ++l) {
    gemm_mfma_k<<<(N_NODES + 127) / 128, 256, 0, stream>>>(hin, w16[l], dinv, h8);
    aggregate_k<<<(N_NODES + 7) / 8, 256, 0, stream>>>(h8, dinv, off, cpack, bl[l], h16);
    hin = h16;
  }

  poolhead_k<<<NGRAPH, 512, 0, stream>>>(h16, batch, fc1w, fc1b, fc2w, fc2b, out);
}

// Round 12
// 259.518 us; speedup vs baseline: 4.5923x; 1.0488x over previous
//
#include <hip/hip_runtime.h>
#include <math.h>

#define N_NODES 50000
#define N_EDGES 1600000
#define HDIM 128
#define NGRAPH 512
#define NCLS 10

#define NSLICE 256
#define EDGES_PER_SLICE (N_EDGES / NSLICE)   // 6250
#define BSH 7                                 // bucket = node >> 7 (128 nodes/bucket)
#define NBUCK 391                             // ceil(N_NODES / 128)

typedef __attribute__((ext_vector_type(8))) short short8v;
typedef __attribute__((ext_vector_type(4))) float float4v;
typedef __attribute__((ext_vector_type(2))) float float2v;

// bf16 helpers
__device__ inline float blo(unsigned int v) { return __uint_as_float(v << 16); }
__device__ inline float bhi(unsigned int v) { return __uint_as_float(v & 0xffff0000u); }
__device__ inline float b2f(unsigned short u) { return __uint_as_float(((unsigned)u) << 16); }
__device__ inline unsigned short f2b(float f) {
  unsigned int u = __float_as_uint(f);
  unsigned int r = u + 0x7fffu + ((u >> 16) & 1u);   // RNE
  return (unsigned short)(r >> 16);
}
// fp8 e4m3 (OCP) hardware converts
__device__ inline unsigned char f2fp8(float f) {
  return (unsigned char)(__builtin_amdgcn_cvt_pk_fp8_f32(f, 0.f, 0, false) & 0xFF);
}
__device__ inline float2v fp8x2lo(unsigned int u) {
  return __builtin_amdgcn_cvt_pk_f32_fp8(u, false);   // bytes 0,1
}
__device__ inline float2v fp8x2hi(unsigned int u) {
  return __builtin_amdgcn_cvt_pk_f32_fp8(u, true);    // bytes 2,3
}

// ---------------- fp32 -> bf16 cast ----------------
__global__ __launch_bounds__(256) void cast4_k(const float* __restrict__ in, unsigned short* __restrict__ out, int n4) {
  int i = blockIdx.x * 256 + threadIdx.x;
  if (i < n4) {
    float4 v = ((const float4*)in)[i];
    ushort4 o;
    o.x = f2b(v.x); o.y = f2b(v.y); o.z = f2b(v.z); o.w = f2b(v.w);
    ((ushort4*)out)[i] = o;
  }
}

// all 4 layer weights in one launch (4 x 16384 fp32, 4 elems/thread)
__global__ __launch_bounds__(256) void castw_k(const float* __restrict__ w0, const float* __restrict__ w1,
                                               const float* __restrict__ w2, const float* __restrict__ w3,
                                               unsigned short* __restrict__ o0, unsigned short* __restrict__ o1,
                                               unsigned short* __restrict__ o2, unsigned short* __restrict__ o3) {
  int i = blockIdx.x * 256 + threadIdx.x;         // 0 .. 16383
  int l = i >> 12, j = i & 4095;                  // 4096 float4 per weight
  const float* in = (l == 0) ? w0 : (l == 1) ? w1 : (l == 2) ? w2 : w3;
  unsigned short* out = (l == 0) ? o0 : (l == 1) ? o1 : (l == 2) ? o2 : o3;
  float4 v = ((const float4*)in)[j];
  ushort4 o;
  o.x = f2b(v.x); o.y = f2b(v.y); o.z = f2b(v.z); o.w = f2b(v.w);
  ((ushort4*)out)[j] = o;
}

// ---------------- phase A1: per-slice coarse-bucket histogram ----------------
__global__ __launch_bounds__(256) void countA_k(const int* __restrict__ ei, int* __restrict__ partialB) {
  __shared__ int cnt[NBUCK];
  int s = blockIdx.x, t = threadIdx.x;
  for (int i = t; i < NBUCK; i += 256) cnt[i] = 0;
  __syncthreads();
  int base = s * EDGES_PER_SLICE;
  for (int i = t; i < EDGES_PER_SLICE; i += 256) {
    int c = ei[N_EDGES + base + i];
    atomicAdd(&cnt[c >> BSH], 1);
  }
  __syncthreads();
  for (int i = t; i < NBUCK; i += 256) partialB[s * NBUCK + i] = cnt[i];
}

// ---------------- phase A2a: per-bucket exclusive prefix over slices ----------------
__global__ __launch_bounds__(256) void prefixA1_k(int* __restrict__ partialB, int* __restrict__ boff) {
  int b = blockIdx.x * 256 + threadIdx.x;
  if (b >= NBUCK) return;
  int acc = 0;
  for (int s = 0; s < NSLICE; ++s) {
    int v = partialB[s * NBUCK + b];
    partialB[s * NBUCK + b] = acc;
    acc += v;
  }
  boff[b] = acc;
}

// ---------------- phase A2b: exclusive scan of bucket totals (1 block) ----------------
__global__ __launch_bounds__(512) void prefixA2_k(int* __restrict__ boff) {
  __shared__ int sd[512];
  int t = threadIdx.x;
  int my = (t < NBUCK) ? boff[t] : 0;
  sd[t] = my;
  __syncthreads();
  for (int d = 1; d < 512; d <<= 1) {
    int v = (t >= d) ? sd[t - d] : 0;
    __syncthreads();
    sd[t] += v;
    __syncthreads();
  }
  if (t < NBUCK) boff[t] = sd[t] - my;
  if (t == 511) boff[NBUCK] = sd[511];
}

// ---------------- phase A3: scatter edges into coarse buckets (packed 8B) ----------------
// record: w(32) << 32 | r(16) << 7 | c_local(7)
__global__ __launch_bounds__(256) void bucketA_k(const int* __restrict__ ei, const float* __restrict__ ew,
                                                 const int* __restrict__ partialB, const int* __restrict__ boff,
                                                 unsigned long long* __restrict__ bucketed) {
  __shared__ int rnk[NBUCK];
  __shared__ int sbase[NBUCK];
  int s = blockIdx.x, t = threadIdx.x;
  for (int i = t; i < NBUCK; i += 256) { rnk[i] = 0; sbase[i] = boff[i] + partialB[s * NBUCK + i]; }
  __syncthreads();
  int base = s * EDGES_PER_SLICE;
  for (int i = t; i < EDGES_PER_SLICE; i += 256) {
    int c = ei[N_EDGES + base + i];
    int r = ei[base + i];
    float w = ew[base + i];
    int bk = c >> BSH;
    int rank = atomicAdd(&rnk[bk], 1);
    unsigned long long v = ((unsigned long long)__float_as_uint(w) << 32)
                         | ((unsigned long long)(unsigned)r << BSH)
                         | (unsigned long long)(c & 127);
    bucketed[(size_t)sbase[bk] + rank] = v;
  }
}

// ---------------- phase B: per-bucket degree + CSR build (fused, block-exclusive) ----------------
// cpack = bf16(w)<<16 | r   (dinv folded into rows / applied at aggregate)
__global__ __launch_bounds__(256) void csrB_k(const unsigned long long* __restrict__ bucketed,
                                              const int* __restrict__ boff,
                                              int* __restrict__ off, float* __restrict__ dinv,
                                              unsigned int* __restrict__ cpack) {
  __shared__ int cnt[128];
  __shared__ float wsum[128];
  __shared__ int sc[128];
  __shared__ int cnt2[128];
  int b = blockIdx.x, t = threadIdx.x;
  if (t < 128) { cnt[t] = 0; cnt2[t] = 0; wsum[t] = 1.0f; }   // self-loop weight
  __syncthreads();
  int s = boff[b], e = boff[b + 1];
  for (int i = s + t; i < e; i += 256) {
    unsigned long long v = bucketed[i];
    atomicAdd(&cnt[(int)(v & 127)], 1);
    atomicAdd(&wsum[(int)(v & 127)], __uint_as_float((unsigned)(v >> 32)));
  }
  __syncthreads();
  if (t < 128) sc[t] = cnt[t];
  __syncthreads();
  for (int d = 1; d < 128; d <<= 1) {
    int v = (t < 128 && t >= d) ? sc[t - d] : 0;
    __syncthreads();
    if (t < 128) sc[t] += v;
    __syncthreads();
  }
  int node = b * 128 + t;
  if (t < 128 && node < N_NODES) {
    off[node] = s + sc[t] - cnt[t];
    dinv[node] = rsqrtf(wsum[t]);
  }
  __syncthreads();
  for (int i = s + t; i < e; i += 256) {
    unsigned long long v = bucketed[i];
    int cl = (int)(v & 127);
    int r = (int)((v >> BSH) & 0xFFFF);
    float w = __uint_as_float((unsigned)(v >> 32));
    int rank = atomicAdd(&cnt2[cl], 1);
    int pos = s + sc[cl] - cnt[cl] + rank;
    cpack[pos] = ((unsigned int)f2b(w) << 16) | (unsigned int)r;
  }
  if (b == 0 && t == 0) off[N_NODES] = N_EDGES;
}

// ---------------- MFMA bf16 GEMM, epilogue: fp8(dinv[row] * acc) ----------------
__global__ __launch_bounds__(256) void gemm_mfma_k(const unsigned short* __restrict__ A,
                                                   const unsigned short* __restrict__ W16,
                                                   const float* __restrict__ dinv,
                                                   unsigned char* __restrict__ Out8) {
  __shared__ unsigned short Wl[128 * 128];
  int t = threadIdx.x;
  for (int idx = t; idx < 2048; idx += 256) {
    int n = idx >> 4, G = idx & 15;
    short8v v = *(const short8v*)(W16 + n * 128 + G * 8);
    int Gs = G ^ (n & 15);
    *(short8v*)(&Wl[n * 128 + Gs * 8]) = v;
  }
  __syncthreads();

  int wave = t >> 6, lane = t & 63;
  int l15 = lane & 15, l4 = lane >> 4;
  int rbase = blockIdx.x * 128 + wave * 32;

  float4v acc[2][8];
#pragma unroll
  for (int m = 0; m < 2; ++m)
#pragma unroll
    for (int f = 0; f < 8; ++f) acc[m][f] = (float4v){0.f, 0.f, 0.f, 0.f};

  int r0 = rbase + l15;        if (r0 >= N_NODES) r0 = N_NODES - 1;
  int r1 = rbase + 16 + l15;   if (r1 >= N_NODES) r1 = N_NODES - 1;

#pragma unroll
  for (int s = 0; s < 4; ++s) {
    int kk = s * 32 + l4 * 8;
    short8v a0 = *(const short8v*)(A + (size_t)r0 * 128 + kk);
    short8v a1 = *(const short8v*)(A + (size_t)r1 * 128 + kk);
#pragma unroll
    for (int f = 0; f < 8; ++f) {
      int n = f * 16 + l15;
      int G = s * 4 + l4;
      int Gs = G ^ (n & 15);
      short8v bfr = *(const short8v*)(&Wl[n * 128 + Gs * 8]);
      acc[0][f] = __builtin_amdgcn_mfma_f32_16x16x32_bf16(a0, bfr, acc[0][f], 0, 0, 0);
      acc[1][f] = __builtin_amdgcn_mfma_f32_16x16x32_bf16(a1, bfr, acc[1][f], 0, 0, 0);
    }
  }

#pragma unroll
  for (int m = 0; m < 2; ++m) {
    int rb = rbase + m * 16 + l4 * 4;
#pragma unroll
    for (int r = 0; r < 4; ++r) {
      int row = rb + r;
      if (row < N_NODES) {
        float ds = dinv[row];
        unsigned char* orow = Out8 + (size_t)row * 128 + l15;
#pragma unroll
        for (int f = 0; f < 8; ++f) orow[f * 16] = f2fp8(acc[m][f][r] * ds);
      }
    }
  }
}

// ---------------- aggregate: out[c] = elu(dinv_c*(h8[c] + sum w*h8[r]) + b) ----------------
// 16 lanes per node (8 fp8 features per lane via u64 gathers), 4 nodes per wave,
// 16 nodes per block. Halves gather-instr + addr-VALU per edge vs 32-lane layout.
__global__ __launch_bounds__(256) void aggregate_k(const unsigned char* __restrict__ h8,
                                                   const float* __restrict__ dinv,
                                                   const int* __restrict__ off,
                                                   const unsigned int* __restrict__ cpack,
                                                   const float* __restrict__ bias,
                                                   unsigned short* __restrict__ hout) {
  int c = blockIdx.x * 16 + (threadIdx.x >> 4);
  if (c >= N_NODES) return;
  int fl = threadIdx.x & 15;            // feature lane: features 8fl..8fl+7
  const uint2* h8q = (const uint2*)h8;  // 16 uint2 per row
  uint2 sv = h8q[((size_t)c << 4) + fl];
  float2v s0 = fp8x2lo(sv.x), s1 = fp8x2hi(sv.x), s2 = fp8x2lo(sv.y), s3 = fp8x2hi(sv.y);
  float a0 = s0.x, a1 = s0.y, a2 = s1.x, a3 = s1.y;
  float a4 = s2.x, a5 = s2.y, a6 = s3.x, a7 = s3.y;
  int s = off[c], e = off[c + 1];
  int k = s;
  for (; k + 8 <= e; k += 8) {
    unsigned int p0 = cpack[k],   p1 = cpack[k+1], p2 = cpack[k+2], p3 = cpack[k+3];
    unsigned int p4 = cpack[k+4], p5 = cpack[k+5], p6 = cpack[k+6], p7 = cpack[k+7];
    uint2 g0 = h8q[((size_t)(p0 & 0xFFFF) << 4) + fl];
    uint2 g1 = h8q[((size_t)(p1 & 0xFFFF) << 4) + fl];
    uint2 g2 = h8q[((size_t)(p2 & 0xFFFF) << 4) + fl];
    uint2 g3 = h8q[((size_t)(p3 & 0xFFFF) << 4) + fl];
    uint2 g4 = h8q[((size_t)(p4 & 0xFFFF) << 4) + fl];
    uint2 g5 = h8q[((size_t)(p5 & 0xFFFF) << 4) + fl];
    uint2 g6 = h8q[((size_t)(p6 & 0xFFFF) << 4) + fl];
    uint2 g7 = h8q[((size_t)(p7 & 0xFFFF) << 4) + fl];
    float w0 = bhi(p0), w1 = bhi(p1), w2 = bhi(p2), w3 = bhi(p3);
    float w4 = bhi(p4), w5 = bhi(p5), w6 = bhi(p6), w7 = bhi(p7);
#define AGG_EDGE(G, W) { \
    float2v q0 = fp8x2lo(G.x), q1 = fp8x2hi(G.x), q2 = fp8x2lo(G.y), q3 = fp8x2hi(G.y); \
    a0 += W * q0.x; a1 += W * q0.y; a2 += W * q1.x; a3 += W * q1.y; \
    a4 += W * q2.x; a5 += W * q2.y; a6 += W * q3.x; a7 += W * q3.y; }
    AGG_EDGE(g0, w0) AGG_EDGE(g1, w1) AGG_EDGE(g2, w2) AGG_EDGE(g3, w3)
    AGG_EDGE(g4, w4) AGG_EDGE(g5, w5) AGG_EDGE(g6, w6) AGG_EDGE(g7, w7)
  }
  for (; k < e; ++k) {
    unsigned int p = cpack[k];
    uint2 g = h8q[((size_t)(p & 0xFFFF) << 4) + fl];
    float w = bhi(p);
    AGG_EDGE(g, w)
  }
#undef AGG_EDGE
  float dc = dinv[c];
  int col = fl * 8;
  float4 b0 = *(const float4*)(bias + col);
  float4 b1 = *(const float4*)(bias + col + 4);
  a0 = dc * a0 + b0.x;  a1 = dc * a1 + b0.y;  a2 = dc * a2 + b0.z;  a3 = dc * a3 + b0.w;
  a4 = dc * a4 + b1.x;  a5 = dc * a5 + b1.y;  a6 = dc * a6 + b1.z;  a7 = dc * a7 + b1.w;
  a0 = a0 > 0.f ? a0 : expm1f(a0);
  a1 = a1 > 0.f ? a1 : expm1f(a1);
  a2 = a2 > 0.f ? a2 : expm1f(a2);
  a3 = a3 > 0.f ? a3 : expm1f(a3);
  a4 = a4 > 0.f ? a4 : expm1f(a4);
  a5 = a5 > 0.f ? a5 : expm1f(a5);
  a6 = a6 > 0.f ? a6 : expm1f(a6);
  a7 = a7 > 0.f ? a7 : expm1f(a7);
  short8v o;
  o[0] = (short)f2b(a0); o[1] = (short)f2b(a1); o[2] = (short)f2b(a2); o[3] = (short)f2b(a3);
  o[4] = (short)f2b(a4); o[5] = (short)f2b(a5); o[6] = (short)f2b(a6); o[7] = (short)f2b(a7);
  *(short8v*)(hout + (size_t)c * 128 + col) = o;
}

// ---------------- fused mean-pool + head: 512 thr = 8 node-groups x 64 lanes ----------------
__global__ __launch_bounds__(512) void poolhead_k(const unsigned short* __restrict__ h,
                                                  const int* __restrict__ batch,
                                                  const float* __restrict__ fc1w, const float* __restrict__ fc1b,
                                                  const float* __restrict__ fc2w, const float* __restrict__ fc2b,
                                                  float* __restrict__ out) {
  __shared__ float part[8][HDIM];
  __shared__ float ps[HDIM];
  __shared__ float z1[HDIM];
  __shared__ float z2[NCLS];
  int g = blockIdx.x, t = threadIdx.x;
  int fl = t & 63;            // u32 word: features 2fl, 2fl+1
  int grp = t >> 6;           // 0..7
  int lo = 0, hi = N_NODES;
  while (lo < hi) { int mid = (lo + hi) >> 1; if (batch[mid] < g) lo = mid + 1; else hi = mid; }
  int gs = lo;
  hi = N_NODES;
  while (lo < hi) { int mid = (lo + hi) >> 1; if (batch[mid] < g + 1) lo = mid + 1; else hi = mid; }
  int ge = lo;
  const unsigned int* hw = (const unsigned int*)h;   // 64 u32 per row
  float a0 = 0.f, a1 = 0.f;
  for (int n = gs + grp; n < ge; n += 8) {
    unsigned int v = hw[((size_t)n << 6) + fl];
    a0 += blo(v); a1 += bhi(v);
  }
  part[grp][fl * 2] = a0;
  part[grp][fl * 2 + 1] = a1;
  __syncthreads();
  if (t < HDIM) {
    float s = 0.f;
#pragma unroll
    for (int q = 0; q < 8; ++q) s += part[q][t];
    ps[t] = s / (float)max(ge - gs, 1);
  }
  __syncthreads();
  if (t < HDIM) {
    float acc = fc1b[t];
    for (int i = 0; i < HDIM; ++i) acc += ps[i] * fc1w[t * HDIM + i];
    z1[t] = (acc > 0.f) ? acc : expm1f(acc);
  }
  __syncthreads();
  if (t < NCLS) {
    float a2 = fc2b[t];
    for (int i = 0; i < HDIM; ++i) a2 += z1[i] * fc2w[t * HDIM + i];
    z2[t] = a2;
  }
  __syncthreads();
  if (t == 0) {
    float m = -1e30f;
    for (int i = 0; i < NCLS; ++i) m = fmaxf(m, z2[i]);
    float s2 = 0.f;
    for (int i = 0; i < NCLS; ++i) s2 += expf(z2[i] - m);
    float l = logf(s2);
    for (int i = 0; i < NCLS; ++i) out[g * NCLS + i] = z2[i] - m - l;
  }
}

// ---------------- launch ----------------
static inline size_t align256(size_t x) { return (x + 255) & ~(size_t)255; }

extern "C" void kernel_launch(void* const* d_in, const int* in_sizes, int n_in,
                              void* d_out, int out_size, void* d_ws, size_t ws_size,
                              hipStream_t stream) {
  const float* x     = (const float*)d_in[0];
  const int*   ei    = (const int*)d_in[1];
  const float* ew    = (const float*)d_in[2];
  const int*   batch = (const int*)d_in[3];
  const float* Wl[4] = { (const float*)d_in[4], (const float*)d_in[6], (const float*)d_in[8], (const float*)d_in[10] };
  const float* bl[4] = { (const float*)d_in[5], (const float*)d_in[7], (const float*)d_in[9], (const float*)d_in[11] };
  const float* fc1w = (const float*)d_in[12];
  const float* fc1b = (const float*)d_in[13];
  const float* fc2w = (const float*)d_in[14];
  const float* fc2b = (const float*)d_in[15];
  float* out = (float*)d_out;

  char* ws = (char*)d_ws;
  size_t o = 0;
  unsigned short* x16 = (unsigned short*)(ws + o); o = align256(o + (size_t)N_NODES * HDIM * 2);
  unsigned short* h16 = (unsigned short*)(ws + o); o = align256(o + (size_t)N_NODES * HDIM * 2);
  // h8 (6.4MB) aliases bucketed (12.8MB): bucketed dead after csrB_k; h8 first
  // written by gemm_mfma_k (launched after csrB_k).
  unsigned char* h8 = (unsigned char*)(ws + o);
  unsigned long long* bucketed = (unsigned long long*)(ws + o);
  o = align256(o + (size_t)N_EDGES * 8);
  unsigned short* w16[4];
  for (int l = 0; l < 4; ++l) { w16[l] = (unsigned short*)(ws + o); o = align256(o + (size_t)HDIM * HDIM * 2); }
  unsigned int* cpack = (unsigned int*)(ws + o); o = align256(o + (size_t)N_EDGES * 4);
  int*   partialB = (int*)(ws + o);   o = align256(o + (size_t)NSLICE * NBUCK * 4);
  int*   boff     = (int*)(ws + o);   o = align256(o + (size_t)(NBUCK + 1) * 4);
  float* dinv  = (float*)(ws + o); o = align256(o + (size_t)N_NODES * 4);
  int*   off   = (int*)  (ws + o); o = align256(o + (size_t)(N_NODES + 1) * 4);

  cast4_k<<<(N_NODES * HDIM / 4 + 255) / 256, 256, 0, stream>>>(x, x16, N_NODES * HDIM / 4);
  castw_k<<<64, 256, 0, stream>>>(Wl[0], Wl[1], Wl[2], Wl[3], w16[0], w16[1], w16[2], w16[3]);

  countA_k<<<NSLICE, 256, 0, stream>>>(ei, partialB);
  prefixA1_k<<<(NBUCK + 255) / 256, 256, 0, stream>>>(partialB, boff);
  prefixA2_k<<<1, 512, 0, stream>>>(boff);
  bucketA_k<<<NSLICE, 256, 0, stream>>>(ei, ew, partialB, boff, bucketed);
  csrB_k<<<NBUCK, 256, 0, stream>>>(bucketed, boff, off, dinv, cpack);

  const unsigned short* hin = x16;
  for (int l = 0; l < 4; ++l) {
    gemm_mfma_k<<<(N_NODES + 127) / 128, 256, 0, stream>>>(hin, w16[l], dinv, h8);
    aggregate_k<<<(N_NODES + 15) / 16, 256, 0, stream>>>(h8, dinv, off, cpack, bl[l], h16);
    hin = h16;
  }

  poolhead_k<<<NGRAPH, 512, 0, stream>>>(h16, batch, fc1w, fc1b, fc2w, fc2b, out);
}